// Round 1
// baseline (2140.482 us; speedup 1.0000x reference)
//
#include <hip/hip_runtime.h>
#include <math.h>

// Problem constants (match reference)
#define HID 256
#define DXIN 128
#define EMBD 32
#define OUTD 128
#define NLAYER 3
#define NGRAPH 8
#define LN_EPS 1e-5f

// ---------------------------------------------------------------------------
// CSR build: histogram, scan, fill
// ---------------------------------------------------------------------------
__global__ void k_hist(const int* __restrict__ dst, int* __restrict__ counts, int E) {
  int e = blockIdx.x * 256 + threadIdx.x;
  if (e < E) atomicAdd(&counts[dst[e]], 1);
}

__global__ void k_bhist(const int* __restrict__ batch, int* __restrict__ pcnt, int N) {
  int i = blockIdx.x * 256 + threadIdx.x;
  if (i < N) atomicAdd(&pcnt[batch[i]], 1);
}

__global__ void k_dinv(const int* __restrict__ counts, float* __restrict__ dinv, int N) {
  int i = blockIdx.x * 256 + threadIdx.x;
  if (i < N) dinv[i] = rsqrtf((float)(counts[i] + 1));  // +1 self loop, always > 0
}

__global__ void k_scan1(const int* __restrict__ counts, int* __restrict__ incl,
                        int* __restrict__ bsums, int N) {
  __shared__ int s[1024];
  int tid = threadIdx.x;
  int i = blockIdx.x * 1024 + tid;
  s[tid] = (i < N) ? counts[i] : 0;
  __syncthreads();
  for (int off = 1; off < 1024; off <<= 1) {
    int t = (tid >= off) ? s[tid - off] : 0;
    __syncthreads();
    s[tid] += t;
    __syncthreads();
  }
  if (i < N) incl[i] = s[tid];
  if (tid == 1023) bsums[blockIdx.x] = s[1023];
}

__global__ void k_scan2(const int* __restrict__ bsums, int* __restrict__ boff, int nb) {
  if (threadIdx.x == 0) {
    int run = 0;
    for (int i = 0; i < nb; ++i) { boff[i] = run; run += bsums[i]; }
  }
}

__global__ void k_scan3(const int* __restrict__ incl, const int* __restrict__ boff,
                        const int* __restrict__ counts, int* __restrict__ row_ptr,
                        int* __restrict__ cursor, int N) {
  int i = blockIdx.x * 1024 + threadIdx.x;
  if (i < N) {
    int inc = incl[i] + boff[blockIdx.x];
    row_ptr[i + 1] = inc;
    cursor[i] = inc - counts[i];
    if (i == 0) row_ptr[0] = 0;
  }
}

__global__ void k_fill(const int* __restrict__ ei, int* __restrict__ cursor,
                       int* __restrict__ col_idx, int E) {
  int e = blockIdx.x * 256 + threadIdx.x;
  if (e < E) {
    int s = ei[e];
    int d = ei[E + e];
    int pos = atomicAdd(&cursor[d], 1);
    col_idx[pos] = s;
  }
}

// ---------------------------------------------------------------------------
// GEMM: input projection  h = relu(concat(x, emb[nt]) @ W_in + b_in)
// Block: 256 threads, 64 rows x 256 cols. Thread: 8 rows x 8 cols.
// ---------------------------------------------------------------------------
__global__ __launch_bounds__(256) void k_gemm_in(
    const float* __restrict__ x, const int* __restrict__ nt, const float* __restrict__ emb,
    const float* __restrict__ W, const float* __restrict__ bias,
    float* __restrict__ h, int N) {
  __shared__ float a_sT[32][68];
  __shared__ int nt_s[64];
  int tid = threadIdx.x;
  int row0 = blockIdx.x * 64;
  int tx = tid & 31, ty = tid >> 5;
  if (tid < 64) {
    int row = row0 + tid;
    nt_s[tid] = (row < N) ? nt[row] : 0;
  }
  float acc[8][8];
#pragma unroll
  for (int i = 0; i < 8; ++i)
#pragma unroll
    for (int j = 0; j < 8; ++j) acc[i][j] = 0.f;
  __syncthreads();
  for (int kt = 0; kt < 5; ++kt) {
#pragma unroll
    for (int i = 0; i < 8; ++i) {
      int l = i * 256 + tid;
      int k = l & 31, r = l >> 5;
      int kg = kt * 32 + k;
      int row = row0 + r;
      float v = 0.f;
      if (row < N) v = (kg < DXIN) ? x[(size_t)row * DXIN + kg]
                                   : emb[nt_s[r] * EMBD + (kg - DXIN)];
      a_sT[k][r] = v;
    }
    __syncthreads();
#pragma unroll 4
    for (int k = 0; k < 32; ++k) {
      int kg = kt * 32 + k;
      float4 w0 = *(const float4*)&W[(size_t)kg * HID + tx * 8];
      float4 w1 = *(const float4*)&W[(size_t)kg * HID + tx * 8 + 4];
      float4 a0 = *(const float4*)&a_sT[k][ty * 8];
      float4 a1 = *(const float4*)&a_sT[k][ty * 8 + 4];
      float av[8] = {a0.x, a0.y, a0.z, a0.w, a1.x, a1.y, a1.z, a1.w};
      float wv[8] = {w0.x, w0.y, w0.z, w0.w, w1.x, w1.y, w1.z, w1.w};
#pragma unroll
      for (int i = 0; i < 8; ++i)
#pragma unroll
        for (int j = 0; j < 8; ++j) acc[i][j] += av[i] * wv[j];
    }
    __syncthreads();
  }
  float bv[8];
#pragma unroll
  for (int j = 0; j < 8; ++j) bv[j] = bias[tx * 8 + j];
#pragma unroll
  for (int i = 0; i < 8; ++i) {
    int row = row0 + ty * 8 + i;
    if (row < N) {
      float4 o0, o1;
      o0.x = fmaxf(acc[i][0] + bv[0], 0.f); o0.y = fmaxf(acc[i][1] + bv[1], 0.f);
      o0.z = fmaxf(acc[i][2] + bv[2], 0.f); o0.w = fmaxf(acc[i][3] + bv[3], 0.f);
      o1.x = fmaxf(acc[i][4] + bv[4], 0.f); o1.y = fmaxf(acc[i][5] + bv[5], 0.f);
      o1.z = fmaxf(acc[i][6] + bv[6], 0.f); o1.w = fmaxf(acc[i][7] + bv[7], 0.f);
      *(float4*)&h[(size_t)row * HID + tx * 8] = o0;
      *(float4*)&h[(size_t)row * HID + tx * 8 + 4] = o1;
    }
  }
}

// ---------------------------------------------------------------------------
// GEMM: square layer  m = h @ W   (K=256, C=256, no bias)
// ---------------------------------------------------------------------------
__global__ __launch_bounds__(256) void k_gemm_sq(
    const float* __restrict__ A, const float* __restrict__ W,
    float* __restrict__ Mout, int N) {
  __shared__ float a_sT[32][68];
  int tid = threadIdx.x;
  int row0 = blockIdx.x * 64;
  int tx = tid & 31, ty = tid >> 5;
  float acc[8][8];
#pragma unroll
  for (int i = 0; i < 8; ++i)
#pragma unroll
    for (int j = 0; j < 8; ++j) acc[i][j] = 0.f;
  for (int kt = 0; kt < 8; ++kt) {
#pragma unroll
    for (int i = 0; i < 8; ++i) {
      int l = i * 256 + tid;
      int k = l & 31, r = l >> 5;
      int row = row0 + r;
      a_sT[k][r] = (row < N) ? A[(size_t)row * HID + kt * 32 + k] : 0.f;
    }
    __syncthreads();
#pragma unroll 4
    for (int k = 0; k < 32; ++k) {
      int kg = kt * 32 + k;
      float4 w0 = *(const float4*)&W[(size_t)kg * HID + tx * 8];
      float4 w1 = *(const float4*)&W[(size_t)kg * HID + tx * 8 + 4];
      float4 a0 = *(const float4*)&a_sT[k][ty * 8];
      float4 a1 = *(const float4*)&a_sT[k][ty * 8 + 4];
      float av[8] = {a0.x, a0.y, a0.z, a0.w, a1.x, a1.y, a1.z, a1.w};
      float wv[8] = {w0.x, w0.y, w0.z, w0.w, w1.x, w1.y, w1.z, w1.w};
#pragma unroll
      for (int i = 0; i < 8; ++i)
#pragma unroll
        for (int j = 0; j < 8; ++j) acc[i][j] += av[i] * wv[j];
    }
    __syncthreads();
  }
#pragma unroll
  for (int i = 0; i < 8; ++i) {
    int row = row0 + ty * 8 + i;
    if (row < N) {
      float4 o0 = make_float4(acc[i][0], acc[i][1], acc[i][2], acc[i][3]);
      float4 o1 = make_float4(acc[i][4], acc[i][5], acc[i][6], acc[i][7]);
      *(float4*)&Mout[(size_t)row * HID + tx * 8] = o0;
      *(float4*)&Mout[(size_t)row * HID + tx * 8 + 4] = o1;
    }
  }
}

// ---------------------------------------------------------------------------
// Fused: GCN aggregation (+bias) -> LayerNorm -> ReLU -> residual (in-place h)
// One block (256 threads) per dst node; thread = one channel.
// ---------------------------------------------------------------------------
__device__ __forceinline__ float block_sum256(float v, float* s_red) {
#pragma unroll
  for (int o = 32; o > 0; o >>= 1) v += __shfl_xor(v, o, 64);
  __syncthreads();
  if ((threadIdx.x & 63) == 0) s_red[threadIdx.x >> 6] = v;
  __syncthreads();
  return s_red[0] + s_red[1] + s_red[2] + s_red[3];
}

__global__ __launch_bounds__(256) void k_agg_ln(
    const float* __restrict__ m, float* __restrict__ h,
    const int* __restrict__ row_ptr, const int* __restrict__ col_idx,
    const float* __restrict__ dinv, const float* __restrict__ bias,
    const float* __restrict__ gamma, const float* __restrict__ beta) {
  __shared__ int s_col[256];
  __shared__ float s_dv[256];
  __shared__ float s_red[4];
  int d = blockIdx.x;
  int c = threadIdx.x;
  float dv = dinv[d];
  float acc = m[(size_t)d * HID + c] * dv;  // self loop (times dv again below)
  int beg = row_ptr[d], end = row_ptr[d + 1];
  for (int base = beg; base < end; base += 256) {
    int j = base + c;
    if (j < end) {
      int s = col_idx[j];
      s_col[c] = s;
      s_dv[c] = dinv[s];
    }
    __syncthreads();
    int cnt = min(256, end - base);
    for (int jj = 0; jj < cnt; ++jj)
      acc += s_dv[jj] * m[(size_t)s_col[jj] * HID + c];
    __syncthreads();
  }
  acc = acc * dv + bias[c];
  float mu = block_sum256(acc, s_red) * (1.f / 256.f);
  float dx = acc - mu;
  float var = block_sum256(dx * dx, s_red) * (1.f / 256.f);
  float y = dx * rsqrtf(var + LN_EPS) * gamma[c] + beta[c];
  h[(size_t)d * HID + c] = fmaxf(y, 0.f) + h[(size_t)d * HID + c];
}

// ---------------------------------------------------------------------------
// Output GEMM (C=128) fused with mean-pool partial sums (batch is sorted).
// ---------------------------------------------------------------------------
__global__ __launch_bounds__(256) void k_gemm_out_pool(
    const float* __restrict__ A, const float* __restrict__ W,
    const float* __restrict__ bias, const int* __restrict__ batch,
    float* __restrict__ psum, int N) {
  __shared__ float a_sT[32][68];
  __shared__ int b_s[64];
  int tid = threadIdx.x;
  int row0 = blockIdx.x * 64;
  int tx = tid & 31, ty = tid >> 5;
  if (tid < 64) {
    int row = row0 + tid;
    b_s[tid] = (row < N) ? batch[row] : -1;
  }
  float acc[8][4];
#pragma unroll
  for (int i = 0; i < 8; ++i)
#pragma unroll
    for (int j = 0; j < 4; ++j) acc[i][j] = 0.f;
  __syncthreads();
  for (int kt = 0; kt < 8; ++kt) {
#pragma unroll
    for (int i = 0; i < 8; ++i) {
      int l = i * 256 + tid;
      int k = l & 31, r = l >> 5;
      int row = row0 + r;
      a_sT[k][r] = (row < N) ? A[(size_t)row * HID + kt * 32 + k] : 0.f;
    }
    __syncthreads();
#pragma unroll 4
    for (int k = 0; k < 32; ++k) {
      int kg = kt * 32 + k;
      float4 w0 = *(const float4*)&W[(size_t)kg * OUTD + tx * 4];
      float4 a0 = *(const float4*)&a_sT[k][ty * 8];
      float4 a1 = *(const float4*)&a_sT[k][ty * 8 + 4];
      float av[8] = {a0.x, a0.y, a0.z, a0.w, a1.x, a1.y, a1.z, a1.w};
      float wv[4] = {w0.x, w0.y, w0.z, w0.w};
#pragma unroll
      for (int i = 0; i < 8; ++i)
#pragma unroll
        for (int j = 0; j < 4; ++j) acc[i][j] += av[i] * wv[j];
    }
    __syncthreads();
  }
  float bv[4];
#pragma unroll
  for (int j = 0; j < 4; ++j) bv[j] = bias[tx * 4 + j];
  // run-wise pooling over this thread's 8 rows
  float run[4] = {0.f, 0.f, 0.f, 0.f};
  int cur = -1;
#pragma unroll
  for (int i = 0; i < 8; ++i) {
    int row = row0 + ty * 8 + i;
    int g = (row < N) ? b_s[ty * 8 + i] : -1;
    if (g != cur) {
      if (cur >= 0) {
#pragma unroll
        for (int j = 0; j < 4; ++j) atomicAdd(&psum[cur * OUTD + tx * 4 + j], run[j]);
      }
#pragma unroll
      for (int j = 0; j < 4; ++j) run[j] = 0.f;
      cur = g;
    }
    if (g >= 0) {
#pragma unroll
      for (int j = 0; j < 4; ++j) run[j] += acc[i][j] + bv[j];
    }
  }
  if (cur >= 0) {
#pragma unroll
    for (int j = 0; j < 4; ++j) atomicAdd(&psum[cur * OUTD + tx * 4 + j], run[j]);
  }
}

__global__ void k_final(const float* __restrict__ psum, const int* __restrict__ pcnt,
                        float* __restrict__ out) {
  int t = threadIdx.x;  // 1024 = 8*128
  int b = t >> 7;
  out[t] = psum[t] / fmaxf((float)pcnt[b], 1.f);
}

// ---------------------------------------------------------------------------
extern "C" void kernel_launch(void* const* d_in, const int* in_sizes, int n_in,
                              void* d_out, int out_size, void* d_ws, size_t ws_size,
                              hipStream_t stream) {
  const float* x      = (const float*)d_in[0];
  const int*   ei     = (const int*)d_in[1];
  const int*   nt     = (const int*)d_in[2];
  const int*   batch  = (const int*)d_in[3];
  const float* emb    = (const float*)d_in[4];
  const float* W_in   = (const float*)d_in[5];
  const float* b_in   = (const float*)d_in[6];
  const float* Ws     = (const float*)d_in[7];
  const float* bs     = (const float*)d_in[8];
  const float* gammas = (const float*)d_in[9];
  const float* betas  = (const float*)d_in[10];
  const float* W_out  = (const float*)d_in[11];
  const float* b_out  = (const float*)d_in[12];
  float* out = (float*)d_out;

  const int N = in_sizes[2];
  const int E = in_sizes[1] / 2;

  // workspace layout (256B aligned regions)
  auto align = [](size_t v) { return (v + 255) & ~(size_t)255; };
  char* p = (char*)d_ws;
  float* h    = (float*)p; p += align((size_t)N * HID * 4);
  float* m    = (float*)p; p += align((size_t)N * HID * 4);
  float* dinv = (float*)p; p += align((size_t)N * 4);
  int* counts = (int*)p;   p += align((size_t)N * 4);
  int* incl   = (int*)p;   p += align((size_t)N * 4);
  int* bsums  = (int*)p;   p += align(64 * 4);
  int* boff   = (int*)p;   p += align(64 * 4);
  int* row_ptr= (int*)p;   p += align((size_t)(N + 1) * 4);
  int* cursor = (int*)p;   p += align((size_t)N * 4);
  int* col_idx= (int*)p;   p += align((size_t)E * 4);
  float* psum = (float*)p; p += align((size_t)NGRAPH * OUTD * 4);
  int* pcnt   = (int*)p;   p += align(NGRAPH * 4);

  hipMemsetAsync(counts, 0, (size_t)N * 4, stream);
  hipMemsetAsync(psum, 0, (size_t)NGRAPH * OUTD * 4, stream);
  hipMemsetAsync(pcnt, 0, NGRAPH * 4, stream);

  const int NB = (N + 1023) / 1024;

  k_hist<<<(E + 255) / 256, 256, 0, stream>>>(ei + E, counts, E);
  k_bhist<<<(N + 255) / 256, 256, 0, stream>>>(batch, pcnt, N);
  k_dinv<<<(N + 255) / 256, 256, 0, stream>>>(counts, dinv, N);
  k_scan1<<<NB, 1024, 0, stream>>>(counts, incl, bsums, N);
  k_scan2<<<1, 64, 0, stream>>>(bsums, boff, NB);
  k_scan3<<<NB, 1024, 0, stream>>>(incl, boff, counts, row_ptr, cursor, N);
  k_fill<<<(E + 255) / 256, 256, 0, stream>>>(ei, cursor, col_idx, E);

  const int GB = (N + 63) / 64;
  k_gemm_in<<<GB, 256, 0, stream>>>(x, nt, emb, W_in, b_in, h, N);

  for (int l = 0; l < NLAYER; ++l) {
    k_gemm_sq<<<GB, 256, 0, stream>>>(h, Ws + (size_t)l * HID * HID, m, N);
    k_agg_ln<<<N, 256, 0, stream>>>(m, h, row_ptr, col_idx, dinv,
                                    bs + (size_t)l * HID, gammas + (size_t)l * HID,
                                    betas + (size_t)l * HID);
  }

  k_gemm_out_pool<<<GB, 256, 0, stream>>>(h, W_out, b_out, batch, psum, N);
  k_final<<<1, 1024, 0, stream>>>(psum, pcnt, out);
}

// Round 2
// 1567.287 us; speedup vs baseline: 1.3657x; 1.3657x over previous
//
#include <hip/hip_runtime.h>
#include <math.h>

// Problem constants (match reference)
#define HID 256
#define DXIN 128
#define EMBD 32
#define OUTD 128
#define NLAYER 3
#define NGRAPH 8
#define LN_EPS 1e-5f

// ---------------------------------------------------------------------------
// CSR build: histogram, scan, fill
// ---------------------------------------------------------------------------
__global__ void k_hist(const int* __restrict__ dst, int* __restrict__ counts, int E) {
  int e = blockIdx.x * 256 + threadIdx.x;
  if (e < E) atomicAdd(&counts[dst[e]], 1);
}

__global__ void k_dinv(const int* __restrict__ counts, float* __restrict__ dinv, int N) {
  int i = blockIdx.x * 256 + threadIdx.x;
  if (i < N) dinv[i] = rsqrtf((float)(counts[i] + 1));  // +1 self loop, always > 0
}

__global__ void k_scan1(const int* __restrict__ counts, int* __restrict__ incl,
                        int* __restrict__ bsums, int N) {
  __shared__ int s[1024];
  int tid = threadIdx.x;
  int i = blockIdx.x * 1024 + tid;
  s[tid] = (i < N) ? counts[i] : 0;
  __syncthreads();
  for (int off = 1; off < 1024; off <<= 1) {
    int t = (tid >= off) ? s[tid - off] : 0;
    __syncthreads();
    s[tid] += t;
    __syncthreads();
  }
  if (i < N) incl[i] = s[tid];
  if (tid == 1023) bsums[blockIdx.x] = s[1023];
}

__global__ void k_scan2(const int* __restrict__ bsums, int* __restrict__ boff, int nb) {
  if (threadIdx.x == 0) {
    int run = 0;
    for (int i = 0; i < nb; ++i) { boff[i] = run; run += bsums[i]; }
  }
}

__global__ void k_scan3(const int* __restrict__ incl, const int* __restrict__ boff,
                        const int* __restrict__ counts, int* __restrict__ row_ptr,
                        int* __restrict__ cursor, int N) {
  int i = blockIdx.x * 1024 + threadIdx.x;
  if (i < N) {
    int inc = incl[i] + boff[blockIdx.x];
    row_ptr[i + 1] = inc;
    cursor[i] = inc - counts[i];
    if (i == 0) row_ptr[0] = 0;
  }
}

__global__ void k_fill(const int* __restrict__ ei, int* __restrict__ cursor,
                       int* __restrict__ col_idx, int E) {
  int e = blockIdx.x * 256 + threadIdx.x;
  if (e < E) {
    int s = ei[e];
    int d = ei[E + e];
    int pos = atomicAdd(&cursor[d], 1);
    col_idx[pos] = s;
  }
}

// ---------------------------------------------------------------------------
// GEMM: input projection  h = relu(concat(x, emb[nt]) @ W_in + b_in)
// Block: 256 threads, 64 rows x 256 cols. Thread: 8 rows x 8 cols.
// ---------------------------------------------------------------------------
__global__ __launch_bounds__(256) void k_gemm_in(
    const float* __restrict__ x, const int* __restrict__ nt, const float* __restrict__ emb,
    const float* __restrict__ W, const float* __restrict__ bias,
    float* __restrict__ h, int N) {
  __shared__ float a_sT[32][68];
  __shared__ int nt_s[64];
  int tid = threadIdx.x;
  int row0 = blockIdx.x * 64;
  int tx = tid & 31, ty = tid >> 5;
  if (tid < 64) {
    int row = row0 + tid;
    nt_s[tid] = (row < N) ? nt[row] : 0;
  }
  float acc[8][8];
#pragma unroll
  for (int i = 0; i < 8; ++i)
#pragma unroll
    for (int j = 0; j < 8; ++j) acc[i][j] = 0.f;
  __syncthreads();
  for (int kt = 0; kt < 5; ++kt) {
#pragma unroll
    for (int i = 0; i < 8; ++i) {
      int l = i * 256 + tid;
      int k = l & 31, r = l >> 5;
      int kg = kt * 32 + k;
      int row = row0 + r;
      float v = 0.f;
      if (row < N) v = (kg < DXIN) ? x[(size_t)row * DXIN + kg]
                                   : emb[nt_s[r] * EMBD + (kg - DXIN)];
      a_sT[k][r] = v;
    }
    __syncthreads();
#pragma unroll 4
    for (int k = 0; k < 32; ++k) {
      int kg = kt * 32 + k;
      float4 w0 = *(const float4*)&W[(size_t)kg * HID + tx * 8];
      float4 w1 = *(const float4*)&W[(size_t)kg * HID + tx * 8 + 4];
      float4 a0 = *(const float4*)&a_sT[k][ty * 8];
      float4 a1 = *(const float4*)&a_sT[k][ty * 8 + 4];
      float av[8] = {a0.x, a0.y, a0.z, a0.w, a1.x, a1.y, a1.z, a1.w};
      float wv[8] = {w0.x, w0.y, w0.z, w0.w, w1.x, w1.y, w1.z, w1.w};
#pragma unroll
      for (int i = 0; i < 8; ++i)
#pragma unroll
        for (int j = 0; j < 8; ++j) acc[i][j] += av[i] * wv[j];
    }
    __syncthreads();
  }
  float bv[8];
#pragma unroll
  for (int j = 0; j < 8; ++j) bv[j] = bias[tx * 8 + j];
#pragma unroll
  for (int i = 0; i < 8; ++i) {
    int row = row0 + ty * 8 + i;
    if (row < N) {
      float4 o0, o1;
      o0.x = fmaxf(acc[i][0] + bv[0], 0.f); o0.y = fmaxf(acc[i][1] + bv[1], 0.f);
      o0.z = fmaxf(acc[i][2] + bv[2], 0.f); o0.w = fmaxf(acc[i][3] + bv[3], 0.f);
      o1.x = fmaxf(acc[i][4] + bv[4], 0.f); o1.y = fmaxf(acc[i][5] + bv[5], 0.f);
      o1.z = fmaxf(acc[i][6] + bv[6], 0.f); o1.w = fmaxf(acc[i][7] + bv[7], 0.f);
      *(float4*)&h[(size_t)row * HID + tx * 8] = o0;
      *(float4*)&h[(size_t)row * HID + tx * 8 + 4] = o1;
    }
  }
}

// ---------------------------------------------------------------------------
// GEMM: square layer  m = h @ W   (K=256, C=256, no bias)
// ---------------------------------------------------------------------------
__global__ __launch_bounds__(256) void k_gemm_sq(
    const float* __restrict__ A, const float* __restrict__ W,
    float* __restrict__ Mout, int N) {
  __shared__ float a_sT[32][68];
  int tid = threadIdx.x;
  int row0 = blockIdx.x * 64;
  int tx = tid & 31, ty = tid >> 5;
  float acc[8][8];
#pragma unroll
  for (int i = 0; i < 8; ++i)
#pragma unroll
    for (int j = 0; j < 8; ++j) acc[i][j] = 0.f;
  for (int kt = 0; kt < 8; ++kt) {
#pragma unroll
    for (int i = 0; i < 8; ++i) {
      int l = i * 256 + tid;
      int k = l & 31, r = l >> 5;
      int row = row0 + r;
      a_sT[k][r] = (row < N) ? A[(size_t)row * HID + kt * 32 + k] : 0.f;
    }
    __syncthreads();
#pragma unroll 4
    for (int k = 0; k < 32; ++k) {
      int kg = kt * 32 + k;
      float4 w0 = *(const float4*)&W[(size_t)kg * HID + tx * 8];
      float4 w1 = *(const float4*)&W[(size_t)kg * HID + tx * 8 + 4];
      float4 a0 = *(const float4*)&a_sT[k][ty * 8];
      float4 a1 = *(const float4*)&a_sT[k][ty * 8 + 4];
      float av[8] = {a0.x, a0.y, a0.z, a0.w, a1.x, a1.y, a1.z, a1.w};
      float wv[8] = {w0.x, w0.y, w0.z, w0.w, w1.x, w1.y, w1.z, w1.w};
#pragma unroll
      for (int i = 0; i < 8; ++i)
#pragma unroll
        for (int j = 0; j < 8; ++j) acc[i][j] += av[i] * wv[j];
    }
    __syncthreads();
  }
#pragma unroll
  for (int i = 0; i < 8; ++i) {
    int row = row0 + ty * 8 + i;
    if (row < N) {
      float4 o0 = make_float4(acc[i][0], acc[i][1], acc[i][2], acc[i][3]);
      float4 o1 = make_float4(acc[i][4], acc[i][5], acc[i][6], acc[i][7]);
      *(float4*)&Mout[(size_t)row * HID + tx * 8] = o0;
      *(float4*)&Mout[(size_t)row * HID + tx * 8 + 4] = o1;
    }
  }
}

// ---------------------------------------------------------------------------
// Fused: GCN aggregation (+bias) -> LayerNorm -> ReLU -> residual (in-place h)
// One block (256 threads) per dst node; thread = one channel.
// ---------------------------------------------------------------------------
__device__ __forceinline__ float block_sum256(float v, float* s_red) {
#pragma unroll
  for (int o = 32; o > 0; o >>= 1) v += __shfl_xor(v, o, 64);
  __syncthreads();
  if ((threadIdx.x & 63) == 0) s_red[threadIdx.x >> 6] = v;
  __syncthreads();
  return s_red[0] + s_red[1] + s_red[2] + s_red[3];
}

__global__ __launch_bounds__(256) void k_agg_ln(
    const float* __restrict__ m, float* __restrict__ h,
    const int* __restrict__ row_ptr, const int* __restrict__ col_idx,
    const float* __restrict__ dinv, const float* __restrict__ bias,
    const float* __restrict__ gamma, const float* __restrict__ beta) {
  __shared__ int s_col[256];
  __shared__ float s_dv[256];
  __shared__ float s_red[4];
  int d = blockIdx.x;
  int c = threadIdx.x;
  float dv = dinv[d];
  float acc = m[(size_t)d * HID + c] * dv;  // self loop (times dv again below)
  int beg = row_ptr[d], end = row_ptr[d + 1];
  for (int base = beg; base < end; base += 256) {
    int j = base + c;
    if (j < end) {
      int s = col_idx[j];
      s_col[c] = s;
      s_dv[c] = dinv[s];
    }
    __syncthreads();
    int cnt = min(256, end - base);
    for (int jj = 0; jj < cnt; ++jj)
      acc += s_dv[jj] * m[(size_t)s_col[jj] * HID + c];
    __syncthreads();
  }
  acc = acc * dv + bias[c];
  float mu = block_sum256(acc, s_red) * (1.f / 256.f);
  float dx = acc - mu;
  float var = block_sum256(dx * dx, s_red) * (1.f / 256.f);
  float y = dx * rsqrtf(var + LN_EPS) * gamma[c] + beta[c];
  h[(size_t)d * HID + c] = fmaxf(y, 0.f) + h[(size_t)d * HID + c];
}

// ---------------------------------------------------------------------------
// Output GEMM (C=128) fused with mean-pool partial sums (batch is sorted).
// ---------------------------------------------------------------------------
__global__ __launch_bounds__(256) void k_gemm_out_pool(
    const float* __restrict__ A, const float* __restrict__ W,
    const float* __restrict__ bias, const int* __restrict__ batch,
    float* __restrict__ psum, int N) {
  __shared__ float a_sT[32][68];
  __shared__ int b_s[64];
  int tid = threadIdx.x;
  int row0 = blockIdx.x * 64;
  int tx = tid & 31, ty = tid >> 5;
  if (tid < 64) {
    int row = row0 + tid;
    b_s[tid] = (row < N) ? batch[row] : -1;
  }
  float acc[8][4];
#pragma unroll
  for (int i = 0; i < 8; ++i)
#pragma unroll
    for (int j = 0; j < 4; ++j) acc[i][j] = 0.f;
  __syncthreads();
  for (int kt = 0; kt < 8; ++kt) {
#pragma unroll
    for (int i = 0; i < 8; ++i) {
      int l = i * 256 + tid;
      int k = l & 31, r = l >> 5;
      int row = row0 + r;
      a_sT[k][r] = (row < N) ? A[(size_t)row * HID + kt * 32 + k] : 0.f;
    }
    __syncthreads();
#pragma unroll 4
    for (int k = 0; k < 32; ++k) {
      int kg = kt * 32 + k;
      float4 w0 = *(const float4*)&W[(size_t)kg * OUTD + tx * 4];
      float4 a0 = *(const float4*)&a_sT[k][ty * 8];
      float4 a1 = *(const float4*)&a_sT[k][ty * 8 + 4];
      float av[8] = {a0.x, a0.y, a0.z, a0.w, a1.x, a1.y, a1.z, a1.w};
      float wv[4] = {w0.x, w0.y, w0.z, w0.w};
#pragma unroll
      for (int i = 0; i < 8; ++i)
#pragma unroll
        for (int j = 0; j < 4; ++j) acc[i][j] += av[i] * wv[j];
    }
    __syncthreads();
  }
  float bv[4];
#pragma unroll
  for (int j = 0; j < 4; ++j) bv[j] = bias[tx * 4 + j];
  // run-wise pooling over this thread's 8 rows
  float run[4] = {0.f, 0.f, 0.f, 0.f};
  int cur = -1;
#pragma unroll
  for (int i = 0; i < 8; ++i) {
    int row = row0 + ty * 8 + i;
    int g = (row < N) ? b_s[ty * 8 + i] : -1;
    if (g != cur) {
      if (cur >= 0) {
#pragma unroll
        for (int j = 0; j < 4; ++j) atomicAdd(&psum[cur * OUTD + tx * 4 + j], run[j]);
      }
#pragma unroll
      for (int j = 0; j < 4; ++j) run[j] = 0.f;
      cur = g;
    }
    if (g >= 0) {
#pragma unroll
      for (int j = 0; j < 4; ++j) run[j] += acc[i][j] + bv[j];
    }
  }
  if (cur >= 0) {
#pragma unroll
    for (int j = 0; j < 4; ++j) atomicAdd(&psum[cur * OUTD + tx * 4 + j], run[j]);
  }
}

// Final: out[b][c] = psum[b][c] / count(batch == b); counts via binary search
// on the sorted batch array (replaces the atomic histogram k_bhist).
__global__ void k_final(const float* __restrict__ psum, const int* __restrict__ batch,
                        float* __restrict__ out, int N) {
  int t = threadIdx.x;  // 1024 = 8*128
  int b = t >> 7;
  // lower bound of b
  int lo = 0, hi = N;
  while (lo < hi) { int mid = (lo + hi) >> 1; if (batch[mid] < b) lo = mid + 1; else hi = mid; }
  int lb = lo;
  // upper bound of b
  lo = 0; hi = N;
  while (lo < hi) { int mid = (lo + hi) >> 1; if (batch[mid] <= b) lo = mid + 1; else hi = mid; }
  int cnt = lo - lb;
  out[t] = psum[t] / fmaxf((float)cnt, 1.f);
}

// ---------------------------------------------------------------------------
extern "C" void kernel_launch(void* const* d_in, const int* in_sizes, int n_in,
                              void* d_out, int out_size, void* d_ws, size_t ws_size,
                              hipStream_t stream) {
  const float* x      = (const float*)d_in[0];
  const int*   ei     = (const int*)d_in[1];
  const int*   nt     = (const int*)d_in[2];
  const int*   batch  = (const int*)d_in[3];
  const float* emb    = (const float*)d_in[4];
  const float* W_in   = (const float*)d_in[5];
  const float* b_in   = (const float*)d_in[6];
  const float* Ws     = (const float*)d_in[7];
  const float* bs     = (const float*)d_in[8];
  const float* gammas = (const float*)d_in[9];
  const float* betas  = (const float*)d_in[10];
  const float* W_out  = (const float*)d_in[11];
  const float* b_out  = (const float*)d_in[12];
  float* out = (float*)d_out;

  const int N = in_sizes[2];
  const int E = in_sizes[1] / 2;

  // workspace layout (256B aligned regions)
  auto align = [](size_t v) { return (v + 255) & ~(size_t)255; };
  char* p = (char*)d_ws;
  float* h    = (float*)p; p += align((size_t)N * HID * 4);
  float* m    = (float*)p; p += align((size_t)N * HID * 4);
  float* dinv = (float*)p; p += align((size_t)N * 4);
  int* counts = (int*)p;   p += align((size_t)N * 4);
  int* incl   = (int*)p;   p += align((size_t)N * 4);
  int* bsums  = (int*)p;   p += align(64 * 4);
  int* boff   = (int*)p;   p += align(64 * 4);
  int* row_ptr= (int*)p;   p += align((size_t)(N + 1) * 4);
  int* cursor = (int*)p;   p += align((size_t)N * 4);
  int* col_idx= (int*)p;   p += align((size_t)E * 4);
  float* psum = (float*)p; p += align((size_t)NGRAPH * OUTD * 4);

  hipMemsetAsync(counts, 0, (size_t)N * 4, stream);
  hipMemsetAsync(psum, 0, (size_t)NGRAPH * OUTD * 4, stream);

  const int NB = (N + 1023) / 1024;

  k_hist<<<(E + 255) / 256, 256, 0, stream>>>(ei + E, counts, E);
  k_dinv<<<(N + 255) / 256, 256, 0, stream>>>(counts, dinv, N);
  k_scan1<<<NB, 1024, 0, stream>>>(counts, incl, bsums, N);
  k_scan2<<<1, 64, 0, stream>>>(bsums, boff, NB);
  k_scan3<<<NB, 1024, 0, stream>>>(incl, boff, counts, row_ptr, cursor, N);
  k_fill<<<(E + 255) / 256, 256, 0, stream>>>(ei, cursor, col_idx, E);

  const int GB = (N + 63) / 64;
  k_gemm_in<<<GB, 256, 0, stream>>>(x, nt, emb, W_in, b_in, h, N);

  for (int l = 0; l < NLAYER; ++l) {
    k_gemm_sq<<<GB, 256, 0, stream>>>(h, Ws + (size_t)l * HID * HID, m, N);
    k_agg_ln<<<N, 256, 0, stream>>>(m, h, row_ptr, col_idx, dinv,
                                    bs + (size_t)l * HID, gammas + (size_t)l * HID,
                                    betas + (size_t)l * HID);
  }

  k_gemm_out_pool<<<GB, 256, 0, stream>>>(h, W_out, b_out, batch, psum, N);
  k_final<<<1, 1024, 0, stream>>>(psum, batch, out, N);
}

// Round 3
// 1385.999 us; speedup vs baseline: 1.5444x; 1.1308x over previous
//
#include <hip/hip_runtime.h>
#include <hip/hip_bf16.h>
#include <math.h>

// Problem constants (match reference)
#define HID 256
#define DXIN 128
#define EMBD 32
#define OUTD 128
#define NLAYER 3
#define NGRAPH 8
#define LN_EPS 1e-5f

// ---------------------------------------------------------------------------
// CSR build: histogram, scan, fill
// ---------------------------------------------------------------------------
__global__ void k_hist(const int* __restrict__ dst, int* __restrict__ counts, int E) {
  int e = blockIdx.x * 256 + threadIdx.x;
  if (e < E) atomicAdd(&counts[dst[e]], 1);
}

__global__ void k_dinv(const int* __restrict__ counts, float* __restrict__ dinv, int N) {
  int i = blockIdx.x * 256 + threadIdx.x;
  if (i < N) dinv[i] = rsqrtf((float)(counts[i] + 1));  // +1 self loop, always > 0
}

__global__ void k_scan1(const int* __restrict__ counts, int* __restrict__ incl,
                        int* __restrict__ bsums, int N) {
  __shared__ int s[1024];
  int tid = threadIdx.x;
  int i = blockIdx.x * 1024 + tid;
  s[tid] = (i < N) ? counts[i] : 0;
  __syncthreads();
  for (int off = 1; off < 1024; off <<= 1) {
    int t = (tid >= off) ? s[tid - off] : 0;
    __syncthreads();
    s[tid] += t;
    __syncthreads();
  }
  if (i < N) incl[i] = s[tid];
  if (tid == 1023) bsums[blockIdx.x] = s[1023];
}

__global__ void k_scan2(const int* __restrict__ bsums, int* __restrict__ boff, int nb) {
  if (threadIdx.x == 0) {
    int run = 0;
    for (int i = 0; i < nb; ++i) { boff[i] = run; run += bsums[i]; }
  }
}

__global__ void k_scan3(const int* __restrict__ incl, const int* __restrict__ boff,
                        const int* __restrict__ counts, int* __restrict__ row_ptr,
                        int* __restrict__ cursor, int N) {
  int i = blockIdx.x * 1024 + threadIdx.x;
  if (i < N) {
    int inc = incl[i] + boff[blockIdx.x];
    row_ptr[i + 1] = inc;
    cursor[i] = inc - counts[i];
    if (i == 0) row_ptr[0] = 0;
  }
}

__global__ void k_fill(const int* __restrict__ ei, int* __restrict__ cursor,
                       int* __restrict__ col_idx, int E) {
  int e = blockIdx.x * 256 + threadIdx.x;
  if (e < E) {
    int s = ei[e];
    int d = ei[E + e];
    int pos = atomicAdd(&cursor[d], 1);
    col_idx[pos] = s;
  }
}

// ---------------------------------------------------------------------------
// GEMM: input projection  h = relu(concat(x, emb[nt]) @ W_in + b_in)
// Block: 256 threads, 64 rows x 256 cols. Thread: 8 rows x 8 cols.
// ---------------------------------------------------------------------------
__global__ __launch_bounds__(256) void k_gemm_in(
    const float* __restrict__ x, const int* __restrict__ nt, const float* __restrict__ emb,
    const float* __restrict__ W, const float* __restrict__ bias,
    float* __restrict__ h, int N) {
  __shared__ float a_sT[32][68];
  __shared__ int nt_s[64];
  int tid = threadIdx.x;
  int row0 = blockIdx.x * 64;
  int tx = tid & 31, ty = tid >> 5;
  if (tid < 64) {
    int row = row0 + tid;
    nt_s[tid] = (row < N) ? nt[row] : 0;
  }
  float acc[8][8];
#pragma unroll
  for (int i = 0; i < 8; ++i)
#pragma unroll
    for (int j = 0; j < 8; ++j) acc[i][j] = 0.f;
  __syncthreads();
  for (int kt = 0; kt < 5; ++kt) {
#pragma unroll
    for (int i = 0; i < 8; ++i) {
      int l = i * 256 + tid;
      int k = l & 31, r = l >> 5;
      int kg = kt * 32 + k;
      int row = row0 + r;
      float v = 0.f;
      if (row < N) v = (kg < DXIN) ? x[(size_t)row * DXIN + kg]
                                   : emb[nt_s[r] * EMBD + (kg - DXIN)];
      a_sT[k][r] = v;
    }
    __syncthreads();
#pragma unroll 4
    for (int k = 0; k < 32; ++k) {
      int kg = kt * 32 + k;
      float4 w0 = *(const float4*)&W[(size_t)kg * HID + tx * 8];
      float4 w1 = *(const float4*)&W[(size_t)kg * HID + tx * 8 + 4];
      float4 a0 = *(const float4*)&a_sT[k][ty * 8];
      float4 a1 = *(const float4*)&a_sT[k][ty * 8 + 4];
      float av[8] = {a0.x, a0.y, a0.z, a0.w, a1.x, a1.y, a1.z, a1.w};
      float wv[8] = {w0.x, w0.y, w0.z, w0.w, w1.x, w1.y, w1.z, w1.w};
#pragma unroll
      for (int i = 0; i < 8; ++i)
#pragma unroll
        for (int j = 0; j < 8; ++j) acc[i][j] += av[i] * wv[j];
    }
    __syncthreads();
  }
  float bv[8];
#pragma unroll
  for (int j = 0; j < 8; ++j) bv[j] = bias[tx * 8 + j];
#pragma unroll
  for (int i = 0; i < 8; ++i) {
    int row = row0 + ty * 8 + i;
    if (row < N) {
      float4 o0, o1;
      o0.x = fmaxf(acc[i][0] + bv[0], 0.f); o0.y = fmaxf(acc[i][1] + bv[1], 0.f);
      o0.z = fmaxf(acc[i][2] + bv[2], 0.f); o0.w = fmaxf(acc[i][3] + bv[3], 0.f);
      o1.x = fmaxf(acc[i][4] + bv[4], 0.f); o1.y = fmaxf(acc[i][5] + bv[5], 0.f);
      o1.z = fmaxf(acc[i][6] + bv[6], 0.f); o1.w = fmaxf(acc[i][7] + bv[7], 0.f);
      *(float4*)&h[(size_t)row * HID + tx * 8] = o0;
      *(float4*)&h[(size_t)row * HID + tx * 8 + 4] = o1;
    }
  }
}

// ---------------------------------------------------------------------------
// GEMM: square layer  m = h @ W   (K=256, C=256, no bias) -> bf16 output
// ---------------------------------------------------------------------------
__global__ __launch_bounds__(256) void k_gemm_sq(
    const float* __restrict__ A, const float* __restrict__ W,
    __hip_bfloat16* __restrict__ Mout, int N) {
  __shared__ float a_sT[32][68];
  int tid = threadIdx.x;
  int row0 = blockIdx.x * 64;
  int tx = tid & 31, ty = tid >> 5;
  float acc[8][8];
#pragma unroll
  for (int i = 0; i < 8; ++i)
#pragma unroll
    for (int j = 0; j < 8; ++j) acc[i][j] = 0.f;
  for (int kt = 0; kt < 8; ++kt) {
#pragma unroll
    for (int i = 0; i < 8; ++i) {
      int l = i * 256 + tid;
      int k = l & 31, r = l >> 5;
      int row = row0 + r;
      a_sT[k][r] = (row < N) ? A[(size_t)row * HID + kt * 32 + k] : 0.f;
    }
    __syncthreads();
#pragma unroll 4
    for (int k = 0; k < 32; ++k) {
      int kg = kt * 32 + k;
      float4 w0 = *(const float4*)&W[(size_t)kg * HID + tx * 8];
      float4 w1 = *(const float4*)&W[(size_t)kg * HID + tx * 8 + 4];
      float4 a0 = *(const float4*)&a_sT[k][ty * 8];
      float4 a1 = *(const float4*)&a_sT[k][ty * 8 + 4];
      float av[8] = {a0.x, a0.y, a0.z, a0.w, a1.x, a1.y, a1.z, a1.w};
      float wv[8] = {w0.x, w0.y, w0.z, w0.w, w1.x, w1.y, w1.z, w1.w};
#pragma unroll
      for (int i = 0; i < 8; ++i)
#pragma unroll
        for (int j = 0; j < 8; ++j) acc[i][j] += av[i] * wv[j];
    }
    __syncthreads();
  }
#pragma unroll
  for (int i = 0; i < 8; ++i) {
    int row = row0 + ty * 8 + i;
    if (row < N) {
      __hip_bfloat16 ob[8];
#pragma unroll
      for (int j = 0; j < 8; ++j) ob[j] = __float2bfloat16(acc[i][j]);
      *(uint4*)&Mout[(size_t)row * HID + tx * 8] = *(const uint4*)ob;
    }
  }
}

// ---------------------------------------------------------------------------
// Fused: GCN aggregation (+bias) -> LayerNorm -> ReLU -> residual (in-place h)
// One block (256 threads) per dst node; thread = one channel. m is bf16.
// ---------------------------------------------------------------------------
__device__ __forceinline__ float block_sum256(float v, float* s_red) {
#pragma unroll
  for (int o = 32; o > 0; o >>= 1) v += __shfl_xor(v, o, 64);
  __syncthreads();
  if ((threadIdx.x & 63) == 0) s_red[threadIdx.x >> 6] = v;
  __syncthreads();
  return s_red[0] + s_red[1] + s_red[2] + s_red[3];
}

__global__ __launch_bounds__(256) void k_agg_ln(
    const __hip_bfloat16* __restrict__ m, float* __restrict__ h,
    const int* __restrict__ row_ptr, const int* __restrict__ col_idx,
    const float* __restrict__ dinv, const float* __restrict__ bias,
    const float* __restrict__ gamma, const float* __restrict__ beta) {
  __shared__ int s_col[256];
  __shared__ float s_dv[256];
  __shared__ float s_red[4];
  int d = blockIdx.x;
  int c = threadIdx.x;
  float dv = dinv[d];
  float acc = __bfloat162float(m[(size_t)d * HID + c]) * dv;  // self loop
  int beg = row_ptr[d], end = row_ptr[d + 1];
  for (int base = beg; base < end; base += 256) {
    int j = base + c;
    if (j < end) {
      int s = col_idx[j];
      s_col[c] = s;
      s_dv[c] = dinv[s];
    }
    __syncthreads();
    int cnt = min(256, end - base);
#pragma unroll 4
    for (int jj = 0; jj < cnt; ++jj) {
      float v = __bfloat162float(m[(size_t)s_col[jj] * HID + c]);
      acc += s_dv[jj] * v;
    }
    __syncthreads();
  }
  acc = acc * dv + bias[c];
  float mu = block_sum256(acc, s_red) * (1.f / 256.f);
  float dx = acc - mu;
  float var = block_sum256(dx * dx, s_red) * (1.f / 256.f);
  float y = dx * rsqrtf(var + LN_EPS) * gamma[c] + beta[c];
  h[(size_t)d * HID + c] = fmaxf(y, 0.f) + h[(size_t)d * HID + c];
}

// ---------------------------------------------------------------------------
// Output GEMM (C=128) fused with mean-pool partial sums (batch is sorted).
// ---------------------------------------------------------------------------
__global__ __launch_bounds__(256) void k_gemm_out_pool(
    const float* __restrict__ A, const float* __restrict__ W,
    const float* __restrict__ bias, const int* __restrict__ batch,
    float* __restrict__ psum, int N) {
  __shared__ float a_sT[32][68];
  __shared__ int b_s[64];
  int tid = threadIdx.x;
  int row0 = blockIdx.x * 64;
  int tx = tid & 31, ty = tid >> 5;
  if (tid < 64) {
    int row = row0 + tid;
    b_s[tid] = (row < N) ? batch[row] : -1;
  }
  float acc[8][4];
#pragma unroll
  for (int i = 0; i < 8; ++i)
#pragma unroll
    for (int j = 0; j < 4; ++j) acc[i][j] = 0.f;
  __syncthreads();
  for (int kt = 0; kt < 8; ++kt) {
#pragma unroll
    for (int i = 0; i < 8; ++i) {
      int l = i * 256 + tid;
      int k = l & 31, r = l >> 5;
      int row = row0 + r;
      a_sT[k][r] = (row < N) ? A[(size_t)row * HID + kt * 32 + k] : 0.f;
    }
    __syncthreads();
#pragma unroll 4
    for (int k = 0; k < 32; ++k) {
      int kg = kt * 32 + k;
      float4 w0 = *(const float4*)&W[(size_t)kg * OUTD + tx * 4];
      float4 a0 = *(const float4*)&a_sT[k][ty * 8];
      float4 a1 = *(const float4*)&a_sT[k][ty * 8 + 4];
      float av[8] = {a0.x, a0.y, a0.z, a0.w, a1.x, a1.y, a1.z, a1.w};
      float wv[4] = {w0.x, w0.y, w0.z, w0.w};
#pragma unroll
      for (int i = 0; i < 8; ++i)
#pragma unroll
        for (int j = 0; j < 4; ++j) acc[i][j] += av[i] * wv[j];
    }
    __syncthreads();
  }
  float bv[4];
#pragma unroll
  for (int j = 0; j < 4; ++j) bv[j] = bias[tx * 4 + j];
  // run-wise pooling over this thread's 8 rows
  float run[4] = {0.f, 0.f, 0.f, 0.f};
  int cur = -1;
#pragma unroll
  for (int i = 0; i < 8; ++i) {
    int row = row0 + ty * 8 + i;
    int g = (row < N) ? b_s[ty * 8 + i] : -1;
    if (g != cur) {
      if (cur >= 0) {
#pragma unroll
        for (int j = 0; j < 4; ++j) atomicAdd(&psum[cur * OUTD + tx * 4 + j], run[j]);
      }
#pragma unroll
      for (int j = 0; j < 4; ++j) run[j] = 0.f;
      cur = g;
    }
    if (g >= 0) {
#pragma unroll
      for (int j = 0; j < 4; ++j) run[j] += acc[i][j] + bv[j];
    }
  }
  if (cur >= 0) {
#pragma unroll
    for (int j = 0; j < 4; ++j) atomicAdd(&psum[cur * OUTD + tx * 4 + j], run[j]);
  }
}

// Final: out[b][c] = psum[b][c] / count(batch == b); counts via binary search
// on the sorted batch array.
__global__ void k_final(const float* __restrict__ psum, const int* __restrict__ batch,
                        float* __restrict__ out, int N) {
  int t = threadIdx.x;  // 1024 = 8*128
  int b = t >> 7;
  int lo = 0, hi = N;
  while (lo < hi) { int mid = (lo + hi) >> 1; if (batch[mid] < b) lo = mid + 1; else hi = mid; }
  int lb = lo;
  lo = 0; hi = N;
  while (lo < hi) { int mid = (lo + hi) >> 1; if (batch[mid] <= b) lo = mid + 1; else hi = mid; }
  int cnt = lo - lb;
  out[t] = psum[t] / fmaxf((float)cnt, 1.f);
}

// ---------------------------------------------------------------------------
extern "C" void kernel_launch(void* const* d_in, const int* in_sizes, int n_in,
                              void* d_out, int out_size, void* d_ws, size_t ws_size,
                              hipStream_t stream) {
  const float* x      = (const float*)d_in[0];
  const int*   ei     = (const int*)d_in[1];
  const int*   nt     = (const int*)d_in[2];
  const int*   batch  = (const int*)d_in[3];
  const float* emb    = (const float*)d_in[4];
  const float* W_in   = (const float*)d_in[5];
  const float* b_in   = (const float*)d_in[6];
  const float* Ws     = (const float*)d_in[7];
  const float* bs     = (const float*)d_in[8];
  const float* gammas = (const float*)d_in[9];
  const float* betas  = (const float*)d_in[10];
  const float* W_out  = (const float*)d_in[11];
  const float* b_out  = (const float*)d_in[12];
  float* out = (float*)d_out;

  const int N = in_sizes[2];
  const int E = in_sizes[1] / 2;

  // workspace layout (256B aligned regions)
  auto align = [](size_t v) { return (v + 255) & ~(size_t)255; };
  char* p = (char*)d_ws;
  float* h    = (float*)p;           p += align((size_t)N * HID * 4);
  __hip_bfloat16* m = (__hip_bfloat16*)p; p += align((size_t)N * HID * 2);
  float* dinv = (float*)p; p += align((size_t)N * 4);
  int* counts = (int*)p;   p += align((size_t)N * 4);
  int* incl   = (int*)p;   p += align((size_t)N * 4);
  int* bsums  = (int*)p;   p += align(64 * 4);
  int* boff   = (int*)p;   p += align(64 * 4);
  int* row_ptr= (int*)p;   p += align((size_t)(N + 1) * 4);
  int* cursor = (int*)p;   p += align((size_t)N * 4);
  int* col_idx= (int*)p;   p += align((size_t)E * 4);
  float* psum = (float*)p; p += align((size_t)NGRAPH * OUTD * 4);

  hipMemsetAsync(counts, 0, (size_t)N * 4, stream);
  hipMemsetAsync(psum, 0, (size_t)NGRAPH * OUTD * 4, stream);

  const int NB = (N + 1023) / 1024;

  k_hist<<<(E + 255) / 256, 256, 0, stream>>>(ei + E, counts, E);
  k_dinv<<<(N + 255) / 256, 256, 0, stream>>>(counts, dinv, N);
  k_scan1<<<NB, 1024, 0, stream>>>(counts, incl, bsums, N);
  k_scan2<<<1, 64, 0, stream>>>(bsums, boff, NB);
  k_scan3<<<NB, 1024, 0, stream>>>(incl, boff, counts, row_ptr, cursor, N);
  k_fill<<<(E + 255) / 256, 256, 0, stream>>>(ei, cursor, col_idx, E);

  const int GB = (N + 63) / 64;
  k_gemm_in<<<GB, 256, 0, stream>>>(x, nt, emb, W_in, b_in, h, N);

  for (int l = 0; l < NLAYER; ++l) {
    k_gemm_sq<<<GB, 256, 0, stream>>>(h, Ws + (size_t)l * HID * HID, m, N);
    k_agg_ln<<<N, 256, 0, stream>>>(m, h, row_ptr, col_idx, dinv,
                                    bs + (size_t)l * HID, gammas + (size_t)l * HID,
                                    betas + (size_t)l * HID);
  }

  k_gemm_out_pool<<<GB, 256, 0, stream>>>(h, W_out, b_out, batch, psum, N);
  k_final<<<1, 1024, 0, stream>>>(psum, batch, out, N);
}

// Round 4
// 830.690 us; speedup vs baseline: 2.5768x; 1.6685x over previous
//
#include <hip/hip_runtime.h>
#include <math.h>

// Problem constants (match reference)
#define HID 256
#define DXIN 128
#define EMBD 32
#define OUTD 128
#define NLAYER 3
#define NGRAPH 8
#define LN_EPS 1e-5f
#define BKP 264   // LDS row stride (bf16 elems): 264*2B = 33 quads, 33%8==1 -> uniform banks

typedef short s8v __attribute__((ext_vector_type(8)));
typedef float f4v __attribute__((ext_vector_type(4)));

__device__ __forceinline__ float b2f(unsigned short u) {
  unsigned int v = ((unsigned int)u) << 16;
  return __builtin_bit_cast(float, v);
}
__device__ __forceinline__ unsigned short f2b(float f) {
  // RTNE bf16 conversion
  unsigned int x = __builtin_bit_cast(unsigned int, f);
  unsigned int lsb = (x >> 16) & 1u;
  x += 0x7fffu + lsb;
  return (unsigned short)(x >> 16);
}

// ---------------------------------------------------------------------------
// CSR build: histogram, scan, fill
// ---------------------------------------------------------------------------
__global__ void k_hist(const int* __restrict__ dst, int* __restrict__ counts, int E) {
  int e = blockIdx.x * 256 + threadIdx.x;
  if (e < E) atomicAdd(&counts[dst[e]], 1);
}

__global__ void k_dinv(const int* __restrict__ counts, float* __restrict__ dinv, int N) {
  int i = blockIdx.x * 256 + threadIdx.x;
  if (i < N) dinv[i] = rsqrtf((float)(counts[i] + 1));
}

__global__ void k_scan1(const int* __restrict__ counts, int* __restrict__ incl,
                        int* __restrict__ bsums, int N) {
  __shared__ int s[1024];
  int tid = threadIdx.x;
  int i = blockIdx.x * 1024 + tid;
  s[tid] = (i < N) ? counts[i] : 0;
  __syncthreads();
  for (int off = 1; off < 1024; off <<= 1) {
    int t = (tid >= off) ? s[tid - off] : 0;
    __syncthreads();
    s[tid] += t;
    __syncthreads();
  }
  if (i < N) incl[i] = s[tid];
  if (tid == 1023) bsums[blockIdx.x] = s[1023];
}

__global__ void k_scan2(const int* __restrict__ bsums, int* __restrict__ boff, int nb) {
  if (threadIdx.x == 0) {
    int run = 0;
    for (int i = 0; i < nb; ++i) { boff[i] = run; run += bsums[i]; }
  }
}

__global__ void k_scan3(const int* __restrict__ incl, const int* __restrict__ boff,
                        const int* __restrict__ counts, int* __restrict__ row_ptr,
                        int* __restrict__ cursor, int N) {
  int i = blockIdx.x * 1024 + threadIdx.x;
  if (i < N) {
    int inc = incl[i] + boff[blockIdx.x];
    row_ptr[i + 1] = inc;
    cursor[i] = inc - counts[i];
    if (i == 0) row_ptr[0] = 0;
  }
}

__global__ void k_fill(const int* __restrict__ ei, int* __restrict__ cursor,
                       int* __restrict__ col_idx, int E) {
  int e = blockIdx.x * 256 + threadIdx.x;
  if (e < E) {
    int s = ei[e];
    int d = ei[E + e];
    int pos = atomicAdd(&cursor[d], 1);
    col_idx[pos] = s;
  }
}

// ---------------------------------------------------------------------------
// Weight pack: W [K][C] fp32 -> bf16 B-fragments.
// dst elem t: j=t&7, l=(t>>3)&63, rest=t>>9, ks=rest%NKS, ct=rest/NKS
//   k = ks*32 + (l>>4)*8 + j ; c = ct*16 + (l&15)
// ---------------------------------------------------------------------------
__global__ void k_pack(const float* __restrict__ W, unsigned short* __restrict__ dst,
                       int C, int NKS, int total) {
  int t = blockIdx.x * 256 + threadIdx.x;
  if (t >= total) return;
  int j = t & 7;
  int l = (t >> 3) & 63;
  int rest = t >> 9;
  int ks = rest % NKS;
  int ct = rest / NKS;
  int k = ks * 32 + ((l >> 4) << 3) + j;
  int c = ct * 16 + (l & 15);
  dst[t] = f2b(W[(size_t)k * C + c]);
}

// ---------------------------------------------------------------------------
// MFMA GEMM: input projection  h = relu(concat(x, emb[nt]) @ W_in + b_in)
// 64 rows x 256 cols per block, 4 waves, K=160 (5 k-steps).
// ---------------------------------------------------------------------------
__global__ __launch_bounds__(256) void k_mfma_in(
    const float* __restrict__ x, const int* __restrict__ nt, const float* __restrict__ emb,
    const unsigned short* __restrict__ Wpk, const float* __restrict__ bias,
    unsigned short* __restrict__ h, int N) {
  __shared__ unsigned short a_lds[64 * BKP];
  int tid = threadIdx.x;
  int w = tid >> 6, l = tid & 63;
  int row0 = blockIdx.x * 64;

  // stage x-part: 64 rows x 16 chunks of 8 fp32 -> bf16
  for (int i = 0; i < 4; ++i) {
    int cc = i * 256 + tid;
    int r = cc >> 4, ch = cc & 15;
    int row = row0 + r;
    unsigned short tmp[8];
    if (row < N) {
      const float* xr = &x[(size_t)row * DXIN + ch * 8];
      float4 v0 = *(const float4*)xr;
      float4 v1 = *(const float4*)(xr + 4);
      tmp[0] = f2b(v0.x); tmp[1] = f2b(v0.y); tmp[2] = f2b(v0.z); tmp[3] = f2b(v0.w);
      tmp[4] = f2b(v1.x); tmp[5] = f2b(v1.y); tmp[6] = f2b(v1.z); tmp[7] = f2b(v1.w);
    } else {
      for (int q = 0; q < 8; ++q) tmp[q] = 0;
    }
    *(uint4*)&a_lds[r * BKP + ch * 8] = *(const uint4*)tmp;
  }
  // stage emb-part: 64 rows x 4 chunks
  {
    int r = tid >> 2, ch = tid & 3;
    int row = row0 + r;
    unsigned short tmp[8];
    if (row < N) {
      int typ = nt[row];
      const float* er = &emb[typ * EMBD + ch * 8];
      float4 v0 = *(const float4*)er;
      float4 v1 = *(const float4*)(er + 4);
      tmp[0] = f2b(v0.x); tmp[1] = f2b(v0.y); tmp[2] = f2b(v0.z); tmp[3] = f2b(v0.w);
      tmp[4] = f2b(v1.x); tmp[5] = f2b(v1.y); tmp[6] = f2b(v1.z); tmp[7] = f2b(v1.w);
    } else {
      for (int q = 0; q < 8; ++q) tmp[q] = 0;
    }
    *(uint4*)&a_lds[r * BKP + DXIN + ch * 8] = *(const uint4*)tmp;
  }
  __syncthreads();

  f4v acc[4][4];
#pragma unroll
  for (int rt = 0; rt < 4; ++rt)
#pragma unroll
    for (int ct = 0; ct < 4; ++ct) acc[rt][ct] = (f4v)0.f;

  for (int ks = 0; ks < 5; ++ks) {
    s8v af[4];
#pragma unroll
    for (int rt = 0; rt < 4; ++rt)
      af[rt] = *(const s8v*)&a_lds[(rt * 16 + (l & 15)) * BKP + ks * 32 + (l >> 4) * 8];
#pragma unroll
    for (int ct = 0; ct < 4; ++ct) {
      s8v bf = *(const s8v*)&Wpk[(size_t)(((w * 4 + ct) * 5 + ks) * 64 + l) * 8];
#pragma unroll
      for (int rt = 0; rt < 4; ++rt)
        acc[rt][ct] = __builtin_amdgcn_mfma_f32_16x16x32_bf16(af[rt], bf, acc[rt][ct], 0, 0, 0);
    }
  }
  __syncthreads();

  // bias + relu + transpose via LDS -> coalesced bf16 store
#pragma unroll
  for (int rt = 0; rt < 4; ++rt)
#pragma unroll
    for (int ct = 0; ct < 4; ++ct) {
      int col = w * 64 + ct * 16 + (l & 15);
      float bv = bias[col];
#pragma unroll
      for (int reg = 0; reg < 4; ++reg) {
        int r = rt * 16 + (l >> 4) * 4 + reg;
        a_lds[r * BKP + col] = f2b(fmaxf(acc[rt][ct][reg] + bv, 0.f));
      }
    }
  __syncthreads();
  for (int i = 0; i < 8; ++i) {
    int cc = i * 256 + tid;
    int r = cc >> 5, ch = cc & 31;
    int row = row0 + r;
    if (row < N)
      *(uint4*)&h[(size_t)row * HID + ch * 8] = *(const uint4*)&a_lds[r * BKP + ch * 8];
  }
}

// ---------------------------------------------------------------------------
// MFMA GEMM: square layer  m = h @ W  (bf16 in/out, K=256)
// ---------------------------------------------------------------------------
__global__ __launch_bounds__(256) void k_mfma_sq(
    const unsigned short* __restrict__ A, const unsigned short* __restrict__ Wpk,
    unsigned short* __restrict__ Mout, int N) {
  __shared__ unsigned short a_lds[64 * BKP];
  int tid = threadIdx.x;
  int w = tid >> 6, l = tid & 63;
  int row0 = blockIdx.x * 64;

  for (int i = 0; i < 8; ++i) {
    int cc = i * 256 + tid;
    int r = cc >> 5, ch = cc & 31;
    int row = row0 + r;
    uint4 v = make_uint4(0u, 0u, 0u, 0u);
    if (row < N) v = *(const uint4*)&A[(size_t)row * HID + ch * 8];
    *(uint4*)&a_lds[r * BKP + ch * 8] = v;
  }
  __syncthreads();

  f4v acc[4][4];
#pragma unroll
  for (int rt = 0; rt < 4; ++rt)
#pragma unroll
    for (int ct = 0; ct < 4; ++ct) acc[rt][ct] = (f4v)0.f;

  for (int ks = 0; ks < 8; ++ks) {
    s8v af[4];
#pragma unroll
    for (int rt = 0; rt < 4; ++rt)
      af[rt] = *(const s8v*)&a_lds[(rt * 16 + (l & 15)) * BKP + ks * 32 + (l >> 4) * 8];
#pragma unroll
    for (int ct = 0; ct < 4; ++ct) {
      s8v bf = *(const s8v*)&Wpk[(size_t)(((w * 4 + ct) * 8 + ks) * 64 + l) * 8];
#pragma unroll
      for (int rt = 0; rt < 4; ++rt)
        acc[rt][ct] = __builtin_amdgcn_mfma_f32_16x16x32_bf16(af[rt], bf, acc[rt][ct], 0, 0, 0);
    }
  }
  __syncthreads();

#pragma unroll
  for (int rt = 0; rt < 4; ++rt)
#pragma unroll
    for (int ct = 0; ct < 4; ++ct) {
      int col = w * 64 + ct * 16 + (l & 15);
#pragma unroll
      for (int reg = 0; reg < 4; ++reg) {
        int r = rt * 16 + (l >> 4) * 4 + reg;
        a_lds[r * BKP + col] = f2b(acc[rt][ct][reg]);
      }
    }
  __syncthreads();
  for (int i = 0; i < 8; ++i) {
    int cc = i * 256 + tid;
    int r = cc >> 5, ch = cc & 31;
    int row = row0 + r;
    if (row < N)
      *(uint4*)&Mout[(size_t)row * HID + ch * 8] = *(const uint4*)&a_lds[r * BKP + ch * 8];
  }
}

// ---------------------------------------------------------------------------
// MFMA GEMM: output layer (C=128) + bias + mean-pool partials via LDS bins.
// ---------------------------------------------------------------------------
__global__ __launch_bounds__(256) void k_mfma_out_pool(
    const unsigned short* __restrict__ A, const unsigned short* __restrict__ Wpk,
    const float* __restrict__ bias, const int* __restrict__ batch,
    float* __restrict__ psum, int N) {
  __shared__ unsigned short a_lds[64 * BKP];
  __shared__ float pool[NGRAPH * OUTD];
  __shared__ int b_s[64];
  int tid = threadIdx.x;
  int w = tid >> 6, l = tid & 63;
  int row0 = blockIdx.x * 64;

#pragma unroll
  for (int i = 0; i < 4; ++i) pool[tid * 4 + i] = 0.f;
  if (tid < 64) b_s[tid] = (row0 + tid < N) ? batch[row0 + tid] : -1;

  for (int i = 0; i < 8; ++i) {
    int cc = i * 256 + tid;
    int r = cc >> 5, ch = cc & 31;
    int row = row0 + r;
    uint4 v = make_uint4(0u, 0u, 0u, 0u);
    if (row < N) v = *(const uint4*)&A[(size_t)row * HID + ch * 8];
    *(uint4*)&a_lds[r * BKP + ch * 8] = v;
  }
  __syncthreads();

  f4v acc[4][2];
#pragma unroll
  for (int rt = 0; rt < 4; ++rt)
#pragma unroll
    for (int ct = 0; ct < 2; ++ct) acc[rt][ct] = (f4v)0.f;

  for (int ks = 0; ks < 8; ++ks) {
    s8v af[4];
#pragma unroll
    for (int rt = 0; rt < 4; ++rt)
      af[rt] = *(const s8v*)&a_lds[(rt * 16 + (l & 15)) * BKP + ks * 32 + (l >> 4) * 8];
#pragma unroll
    for (int ct = 0; ct < 2; ++ct) {
      s8v bf = *(const s8v*)&Wpk[(size_t)(((w * 2 + ct) * 8 + ks) * 64 + l) * 8];
#pragma unroll
      for (int rt = 0; rt < 4; ++rt)
        acc[rt][ct] = __builtin_amdgcn_mfma_f32_16x16x32_bf16(af[rt], bf, acc[rt][ct], 0, 0, 0);
    }
  }

  // pool into LDS bins (rows visited in increasing order -> run detection ok)
#pragma unroll
  for (int ct = 0; ct < 2; ++ct) {
    int col = w * 32 + ct * 16 + (l & 15);
    float bv = bias[col];
    float run = 0.f;
    int cur = -1;
#pragma unroll
    for (int rt = 0; rt < 4; ++rt)
#pragma unroll
      for (int reg = 0; reg < 4; ++reg) {
        int rrel = rt * 16 + (l >> 4) * 4 + reg;
        int g = b_s[rrel];
        if (g != cur) {
          if (cur >= 0) atomicAdd(&pool[cur * OUTD + col], run);
          run = 0.f;
          cur = g;
        }
        if (g >= 0) run += acc[rt][ct][reg] + bv;
      }
    if (cur >= 0) atomicAdd(&pool[cur * OUTD + col], run);
  }
  __syncthreads();
#pragma unroll
  for (int i = 0; i < 4; ++i) {
    int idx = tid * 4 + i;
    float v = pool[idx];
    if (v != 0.f) atomicAdd(&psum[idx], v);
  }
}

// ---------------------------------------------------------------------------
// Fused: GCN aggregation (+bias) -> LayerNorm -> ReLU -> residual (h bf16)
// ---------------------------------------------------------------------------
__device__ __forceinline__ float block_sum256(float v, float* s_red) {
#pragma unroll
  for (int o = 32; o > 0; o >>= 1) v += __shfl_xor(v, o, 64);
  __syncthreads();
  if ((threadIdx.x & 63) == 0) s_red[threadIdx.x >> 6] = v;
  __syncthreads();
  return s_red[0] + s_red[1] + s_red[2] + s_red[3];
}

__global__ __launch_bounds__(256) void k_agg_ln(
    const unsigned short* __restrict__ m, unsigned short* __restrict__ h,
    const int* __restrict__ row_ptr, const int* __restrict__ col_idx,
    const float* __restrict__ dinv, const float* __restrict__ bias,
    const float* __restrict__ gamma, const float* __restrict__ beta) {
  __shared__ int s_col[256];
  __shared__ float s_dv[256];
  __shared__ float s_red[4];
  int d = blockIdx.x;
  int c = threadIdx.x;
  float dv = dinv[d];
  float acc = b2f(m[(size_t)d * HID + c]) * dv;  // self loop
  int beg = row_ptr[d], end = row_ptr[d + 1];
  for (int base = beg; base < end; base += 256) {
    int j = base + c;
    if (j < end) {
      int s = col_idx[j];
      s_col[c] = s;
      s_dv[c] = dinv[s];
    }
    __syncthreads();
    int cnt = min(256, end - base);
#pragma unroll 4
    for (int jj = 0; jj < cnt; ++jj) {
      float v = b2f(m[(size_t)s_col[jj] * HID + c]);
      acc += s_dv[jj] * v;
    }
    __syncthreads();
  }
  acc = acc * dv + bias[c];
  float mu = block_sum256(acc, s_red) * (1.f / 256.f);
  float dx = acc - mu;
  float var = block_sum256(dx * dx, s_red) * (1.f / 256.f);
  float y = dx * rsqrtf(var + LN_EPS) * gamma[c] + beta[c];
  float res = b2f(h[(size_t)d * HID + c]);
  h[(size_t)d * HID + c] = f2b(fmaxf(y, 0.f) + res);
}

// Final: out[b][c] = psum[b][c] / count(batch==b); counts via binary search.
__global__ void k_final(const float* __restrict__ psum, const int* __restrict__ batch,
                        float* __restrict__ out, int N) {
  int t = threadIdx.x;  // 1024 = 8*128
  int b = t >> 7;
  int lo = 0, hi = N;
  while (lo < hi) { int mid = (lo + hi) >> 1; if (batch[mid] < b) lo = mid + 1; else hi = mid; }
  int lb = lo;
  lo = 0; hi = N;
  while (lo < hi) { int mid = (lo + hi) >> 1; if (batch[mid] <= b) lo = mid + 1; else hi = mid; }
  int cnt = lo - lb;
  out[t] = psum[t] / fmaxf((float)cnt, 1.f);
}

// ---------------------------------------------------------------------------
extern "C" void kernel_launch(void* const* d_in, const int* in_sizes, int n_in,
                              void* d_out, int out_size, void* d_ws, size_t ws_size,
                              hipStream_t stream) {
  const float* x      = (const float*)d_in[0];
  const int*   ei     = (const int*)d_in[1];
  const int*   nt     = (const int*)d_in[2];
  const int*   batch  = (const int*)d_in[3];
  const float* emb    = (const float*)d_in[4];
  const float* W_in   = (const float*)d_in[5];
  const float* b_in   = (const float*)d_in[6];
  const float* Ws     = (const float*)d_in[7];
  const float* bs     = (const float*)d_in[8];
  const float* gammas = (const float*)d_in[9];
  const float* betas  = (const float*)d_in[10];
  const float* W_out  = (const float*)d_in[11];
  const float* b_out  = (const float*)d_in[12];
  float* out = (float*)d_out;

  const int N = in_sizes[2];
  const int E = in_sizes[1] / 2;

  auto align = [](size_t v) { return (v + 255) & ~(size_t)255; };
  char* p = (char*)d_ws;
  unsigned short* h = (unsigned short*)p; p += align((size_t)N * HID * 2);
  unsigned short* m = (unsigned short*)p; p += align((size_t)N * HID * 2);
  unsigned short* pk_in  = (unsigned short*)p; p += align(16 * 5 * 512 * 2);
  unsigned short* pk_sq  = (unsigned short*)p; p += align((size_t)3 * 16 * 8 * 512 * 2);
  unsigned short* pk_out = (unsigned short*)p; p += align(8 * 8 * 512 * 2);
  float* dinv = (float*)p; p += align((size_t)N * 4);
  int* counts = (int*)p;   p += align((size_t)N * 4);
  int* incl   = (int*)p;   p += align((size_t)N * 4);
  int* bsums  = (int*)p;   p += align(64 * 4);
  int* boff   = (int*)p;   p += align(64 * 4);
  int* row_ptr= (int*)p;   p += align((size_t)(N + 1) * 4);
  int* cursor = (int*)p;   p += align((size_t)N * 4);
  int* col_idx= (int*)p;   p += align((size_t)E * 4);
  float* psum = (float*)p; p += align((size_t)NGRAPH * OUTD * 4);

  hipMemsetAsync(counts, 0, (size_t)N * 4, stream);
  hipMemsetAsync(psum, 0, (size_t)NGRAPH * OUTD * 4, stream);

  // weight packing (tiny, one-time per launch)
  {
    int t_in = 16 * 5 * 512;
    k_pack<<<(t_in + 255) / 256, 256, 0, stream>>>(W_in, pk_in, HID, 5, t_in);
    int t_sq = 16 * 8 * 512;
    for (int lyr = 0; lyr < NLAYER; ++lyr)
      k_pack<<<(t_sq + 255) / 256, 256, 0, stream>>>(Ws + (size_t)lyr * HID * HID,
                                                     pk_sq + (size_t)lyr * t_sq, HID, 8, t_sq);
    int t_out = 8 * 8 * 512;
    k_pack<<<(t_out + 255) / 256, 256, 0, stream>>>(W_out, pk_out, OUTD, 8, t_out);
  }

  const int NB = (N + 1023) / 1024;
  k_hist<<<(E + 255) / 256, 256, 0, stream>>>(ei + E, counts, E);
  k_dinv<<<(N + 255) / 256, 256, 0, stream>>>(counts, dinv, N);
  k_scan1<<<NB, 1024, 0, stream>>>(counts, incl, bsums, N);
  k_scan2<<<1, 64, 0, stream>>>(bsums, boff, NB);
  k_scan3<<<NB, 1024, 0, stream>>>(incl, boff, counts, row_ptr, cursor, N);
  k_fill<<<(E + 255) / 256, 256, 0, stream>>>(ei, cursor, col_idx, E);

  const int GB = (N + 63) / 64;
  k_mfma_in<<<GB, 256, 0, stream>>>(x, nt, emb, pk_in, b_in, h, N);

  for (int lyr = 0; lyr < NLAYER; ++lyr) {
    k_mfma_sq<<<GB, 256, 0, stream>>>(h, pk_sq + (size_t)lyr * 16 * 8 * 512, m, N);
    k_agg_ln<<<N, 256, 0, stream>>>(m, h, row_ptr, col_idx, dinv,
                                    bs + (size_t)lyr * HID, gammas + (size_t)lyr * HID,
                                    betas + (size_t)lyr * HID);
  }

  k_mfma_out_pool<<<GB, 256, 0, stream>>>(h, pk_out, b_out, batch, psum, N);
  k_final<<<1, 1024, 0, stream>>>(psum, batch, out, N);
}

// Round 5
// 672.972 us; speedup vs baseline: 3.1806x; 1.2344x over previous
//
#include <hip/hip_runtime.h>
#include <math.h>

// Problem constants (match reference)
#define HID 256
#define DXIN 128
#define EMBD 32
#define OUTD 128
#define NLAYER 3
#define NGRAPH 8
#define LN_EPS 1e-5f
#define BKP 264   // LDS row stride (bf16 elems): 264*2B = 33 quads, 33%8==1 -> uniform banks

typedef short s8v __attribute__((ext_vector_type(8)));
typedef float f4v __attribute__((ext_vector_type(4)));

__device__ __forceinline__ float b2f(unsigned short u) {
  unsigned int v = ((unsigned int)u) << 16;
  return __builtin_bit_cast(float, v);
}
__device__ __forceinline__ float b2f_lo(unsigned int u) {
  return __builtin_bit_cast(float, u << 16);
}
__device__ __forceinline__ float b2f_hi(unsigned int u) {
  return __builtin_bit_cast(float, u & 0xffff0000u);
}
__device__ __forceinline__ unsigned short f2b(float f) {
  // RTNE bf16 conversion
  unsigned int x = __builtin_bit_cast(unsigned int, f);
  unsigned int lsb = (x >> 16) & 1u;
  x += 0x7fffu + lsb;
  return (unsigned short)(x >> 16);
}

// ---------------------------------------------------------------------------
// CSR build: histogram, scan, fill
// ---------------------------------------------------------------------------
__global__ void k_hist(const int* __restrict__ dst, int* __restrict__ counts, int E) {
  int e = blockIdx.x * 256 + threadIdx.x;
  if (e < E) atomicAdd(&counts[dst[e]], 1);
}

__global__ void k_dinv(const int* __restrict__ counts, float* __restrict__ dinv, int N) {
  int i = blockIdx.x * 256 + threadIdx.x;
  if (i < N) dinv[i] = rsqrtf((float)(counts[i] + 1));
}

__global__ void k_scan1(const int* __restrict__ counts, int* __restrict__ incl,
                        int* __restrict__ bsums, int N) {
  __shared__ int s[1024];
  int tid = threadIdx.x;
  int i = blockIdx.x * 1024 + tid;
  s[tid] = (i < N) ? counts[i] : 0;
  __syncthreads();
  for (int off = 1; off < 1024; off <<= 1) {
    int t = (tid >= off) ? s[tid - off] : 0;
    __syncthreads();
    s[tid] += t;
    __syncthreads();
  }
  if (i < N) incl[i] = s[tid];
  if (tid == 1023) bsums[blockIdx.x] = s[1023];
}

__global__ void k_scan2(const int* __restrict__ bsums, int* __restrict__ boff, int nb) {
  if (threadIdx.x == 0) {
    int run = 0;
    for (int i = 0; i < nb; ++i) { boff[i] = run; run += bsums[i]; }
  }
}

__global__ void k_scan3(const int* __restrict__ incl, const int* __restrict__ boff,
                        const int* __restrict__ counts, int* __restrict__ row_ptr,
                        int* __restrict__ cursor, int N) {
  int i = blockIdx.x * 1024 + threadIdx.x;
  if (i < N) {
    int inc = incl[i] + boff[blockIdx.x];
    row_ptr[i + 1] = inc;
    cursor[i] = inc - counts[i];
    if (i == 0) row_ptr[0] = 0;
  }
}

__global__ void k_fill(const int* __restrict__ ei, int* __restrict__ cursor,
                       int* __restrict__ col_idx, int E) {
  int e = blockIdx.x * 256 + threadIdx.x;
  if (e < E) {
    int s = ei[e];
    int d = ei[E + e];
    int pos = atomicAdd(&cursor[d], 1);
    col_idx[pos] = s;
  }
}

// ---------------------------------------------------------------------------
// Weight pack: W [K][C] fp32 -> bf16 B-fragments.
// dst elem t: j=t&7, l=(t>>3)&63, rest=t>>9, ks=rest%NKS, ct=rest/NKS
//   k = ks*32 + (l>>4)*8 + j ; c = ct*16 + (l&15)
// ---------------------------------------------------------------------------
__global__ void k_pack(const float* __restrict__ W, unsigned short* __restrict__ dst,
                       int C, int NKS, int total) {
  int t = blockIdx.x * 256 + threadIdx.x;
  if (t >= total) return;
  int j = t & 7;
  int l = (t >> 3) & 63;
  int rest = t >> 9;
  int ks = rest % NKS;
  int ct = rest / NKS;
  int k = ks * 32 + ((l >> 4) << 3) + j;
  int c = ct * 16 + (l & 15);
  dst[t] = f2b(W[(size_t)k * C + c]);
}

// ---------------------------------------------------------------------------
// MFMA GEMM: input projection  h = relu(concat(x, emb[nt]) @ W_in + b_in)
// 64 rows x 256 cols per block, 4 waves, K=160 (5 k-steps).
// ---------------------------------------------------------------------------
__global__ __launch_bounds__(256) void k_mfma_in(
    const float* __restrict__ x, const int* __restrict__ nt, const float* __restrict__ emb,
    const unsigned short* __restrict__ Wpk, const float* __restrict__ bias,
    unsigned short* __restrict__ h, int N) {
  __shared__ unsigned short a_lds[64 * BKP];
  int tid = threadIdx.x;
  int w = tid >> 6, l = tid & 63;
  int row0 = blockIdx.x * 64;

  // stage x-part: 64 rows x 16 chunks of 8 fp32 -> bf16
  for (int i = 0; i < 4; ++i) {
    int cc = i * 256 + tid;
    int r = cc >> 4, ch = cc & 15;
    int row = row0 + r;
    unsigned short tmp[8];
    if (row < N) {
      const float* xr = &x[(size_t)row * DXIN + ch * 8];
      float4 v0 = *(const float4*)xr;
      float4 v1 = *(const float4*)(xr + 4);
      tmp[0] = f2b(v0.x); tmp[1] = f2b(v0.y); tmp[2] = f2b(v0.z); tmp[3] = f2b(v0.w);
      tmp[4] = f2b(v1.x); tmp[5] = f2b(v1.y); tmp[6] = f2b(v1.z); tmp[7] = f2b(v1.w);
    } else {
      for (int q = 0; q < 8; ++q) tmp[q] = 0;
    }
    *(uint4*)&a_lds[r * BKP + ch * 8] = *(const uint4*)tmp;
  }
  // stage emb-part: 64 rows x 4 chunks
  {
    int r = tid >> 2, ch = tid & 3;
    int row = row0 + r;
    unsigned short tmp[8];
    if (row < N) {
      int typ = nt[row];
      const float* er = &emb[typ * EMBD + ch * 8];
      float4 v0 = *(const float4*)er;
      float4 v1 = *(const float4*)(er + 4);
      tmp[0] = f2b(v0.x); tmp[1] = f2b(v0.y); tmp[2] = f2b(v0.z); tmp[3] = f2b(v0.w);
      tmp[4] = f2b(v1.x); tmp[5] = f2b(v1.y); tmp[6] = f2b(v1.z); tmp[7] = f2b(v1.w);
    } else {
      for (int q = 0; q < 8; ++q) tmp[q] = 0;
    }
    *(uint4*)&a_lds[r * BKP + DXIN + ch * 8] = *(const uint4*)tmp;
  }
  __syncthreads();

  f4v acc[4][4];
#pragma unroll
  for (int rt = 0; rt < 4; ++rt)
#pragma unroll
    for (int ct = 0; ct < 4; ++ct) acc[rt][ct] = (f4v)0.f;

  for (int ks = 0; ks < 5; ++ks) {
    s8v af[4];
#pragma unroll
    for (int rt = 0; rt < 4; ++rt)
      af[rt] = *(const s8v*)&a_lds[(rt * 16 + (l & 15)) * BKP + ks * 32 + (l >> 4) * 8];
#pragma unroll
    for (int ct = 0; ct < 4; ++ct) {
      s8v bf = *(const s8v*)&Wpk[(size_t)(((w * 4 + ct) * 5 + ks) * 64 + l) * 8];
#pragma unroll
      for (int rt = 0; rt < 4; ++rt)
        acc[rt][ct] = __builtin_amdgcn_mfma_f32_16x16x32_bf16(af[rt], bf, acc[rt][ct], 0, 0, 0);
    }
  }
  __syncthreads();

  // bias + relu + transpose via LDS -> coalesced bf16 store
#pragma unroll
  for (int rt = 0; rt < 4; ++rt)
#pragma unroll
    for (int ct = 0; ct < 4; ++ct) {
      int col = w * 64 + ct * 16 + (l & 15);
      float bv = bias[col];
#pragma unroll
      for (int reg = 0; reg < 4; ++reg) {
        int r = rt * 16 + (l >> 4) * 4 + reg;
        a_lds[r * BKP + col] = f2b(fmaxf(acc[rt][ct][reg] + bv, 0.f));
      }
    }
  __syncthreads();
  for (int i = 0; i < 8; ++i) {
    int cc = i * 256 + tid;
    int r = cc >> 5, ch = cc & 31;
    int row = row0 + r;
    if (row < N)
      *(uint4*)&h[(size_t)row * HID + ch * 8] = *(const uint4*)&a_lds[r * BKP + ch * 8];
  }
}

// ---------------------------------------------------------------------------
// MFMA GEMM: square layer  m = h @ W  (bf16 in/out, K=256)
// ---------------------------------------------------------------------------
__global__ __launch_bounds__(256) void k_mfma_sq(
    const unsigned short* __restrict__ A, const unsigned short* __restrict__ Wpk,
    unsigned short* __restrict__ Mout, int N) {
  __shared__ unsigned short a_lds[64 * BKP];
  int tid = threadIdx.x;
  int w = tid >> 6, l = tid & 63;
  int row0 = blockIdx.x * 64;

  for (int i = 0; i < 8; ++i) {
    int cc = i * 256 + tid;
    int r = cc >> 5, ch = cc & 31;
    int row = row0 + r;
    uint4 v = make_uint4(0u, 0u, 0u, 0u);
    if (row < N) v = *(const uint4*)&A[(size_t)row * HID + ch * 8];
    *(uint4*)&a_lds[r * BKP + ch * 8] = v;
  }
  __syncthreads();

  f4v acc[4][4];
#pragma unroll
  for (int rt = 0; rt < 4; ++rt)
#pragma unroll
    for (int ct = 0; ct < 4; ++ct) acc[rt][ct] = (f4v)0.f;

  for (int ks = 0; ks < 8; ++ks) {
    s8v af[4];
#pragma unroll
    for (int rt = 0; rt < 4; ++rt)
      af[rt] = *(const s8v*)&a_lds[(rt * 16 + (l & 15)) * BKP + ks * 32 + (l >> 4) * 8];
#pragma unroll
    for (int ct = 0; ct < 4; ++ct) {
      s8v bf = *(const s8v*)&Wpk[(size_t)(((w * 4 + ct) * 8 + ks) * 64 + l) * 8];
#pragma unroll
      for (int rt = 0; rt < 4; ++rt)
        acc[rt][ct] = __builtin_amdgcn_mfma_f32_16x16x32_bf16(af[rt], bf, acc[rt][ct], 0, 0, 0);
    }
  }
  __syncthreads();

#pragma unroll
  for (int rt = 0; rt < 4; ++rt)
#pragma unroll
    for (int ct = 0; ct < 4; ++ct) {
      int col = w * 64 + ct * 16 + (l & 15);
#pragma unroll
      for (int reg = 0; reg < 4; ++reg) {
        int r = rt * 16 + (l >> 4) * 4 + reg;
        a_lds[r * BKP + col] = f2b(acc[rt][ct][reg]);
      }
    }
  __syncthreads();
  for (int i = 0; i < 8; ++i) {
    int cc = i * 256 + tid;
    int r = cc >> 5, ch = cc & 31;
    int row = row0 + r;
    if (row < N)
      *(uint4*)&Mout[(size_t)row * HID + ch * 8] = *(const uint4*)&a_lds[r * BKP + ch * 8];
  }
}

// ---------------------------------------------------------------------------
// MFMA GEMM: output layer (C=128) + bias + mean-pool partials via LDS bins.
// ---------------------------------------------------------------------------
__global__ __launch_bounds__(256) void k_mfma_out_pool(
    const unsigned short* __restrict__ A, const unsigned short* __restrict__ Wpk,
    const float* __restrict__ bias, const int* __restrict__ batch,
    float* __restrict__ psum, int N) {
  __shared__ unsigned short a_lds[64 * BKP];
  __shared__ float pool[NGRAPH * OUTD];
  __shared__ int b_s[64];
  int tid = threadIdx.x;
  int w = tid >> 6, l = tid & 63;
  int row0 = blockIdx.x * 64;

#pragma unroll
  for (int i = 0; i < 4; ++i) pool[tid * 4 + i] = 0.f;
  if (tid < 64) b_s[tid] = (row0 + tid < N) ? batch[row0 + tid] : -1;

  for (int i = 0; i < 8; ++i) {
    int cc = i * 256 + tid;
    int r = cc >> 5, ch = cc & 31;
    int row = row0 + r;
    uint4 v = make_uint4(0u, 0u, 0u, 0u);
    if (row < N) v = *(const uint4*)&A[(size_t)row * HID + ch * 8];
    *(uint4*)&a_lds[r * BKP + ch * 8] = v;
  }
  __syncthreads();

  f4v acc[4][2];
#pragma unroll
  for (int rt = 0; rt < 4; ++rt)
#pragma unroll
    for (int ct = 0; ct < 2; ++ct) acc[rt][ct] = (f4v)0.f;

  for (int ks = 0; ks < 8; ++ks) {
    s8v af[4];
#pragma unroll
    for (int rt = 0; rt < 4; ++rt)
      af[rt] = *(const s8v*)&a_lds[(rt * 16 + (l & 15)) * BKP + ks * 32 + (l >> 4) * 8];
#pragma unroll
    for (int ct = 0; ct < 2; ++ct) {
      s8v bf = *(const s8v*)&Wpk[(size_t)(((w * 2 + ct) * 8 + ks) * 64 + l) * 8];
#pragma unroll
      for (int rt = 0; rt < 4; ++rt)
        acc[rt][ct] = __builtin_amdgcn_mfma_f32_16x16x32_bf16(af[rt], bf, acc[rt][ct], 0, 0, 0);
    }
  }

  // pool into LDS bins (rows visited in increasing order -> run detection ok)
#pragma unroll
  for (int ct = 0; ct < 2; ++ct) {
    int col = w * 32 + ct * 16 + (l & 15);
    float bv = bias[col];
    float run = 0.f;
    int cur = -1;
#pragma unroll
    for (int rt = 0; rt < 4; ++rt)
#pragma unroll
      for (int reg = 0; reg < 4; ++reg) {
        int rrel = rt * 16 + (l >> 4) * 4 + reg;
        int g = b_s[rrel];
        if (g != cur) {
          if (cur >= 0) atomicAdd(&pool[cur * OUTD + col], run);
          run = 0.f;
          cur = g;
        }
        if (g >= 0) run += acc[rt][ct][reg] + bv;
      }
    if (cur >= 0) atomicAdd(&pool[cur * OUTD + col], run);
  }
  __syncthreads();
#pragma unroll
  for (int i = 0; i < 4; ++i) {
    int idx = tid * 4 + i;
    float v = pool[idx];
    if (v != 0.f) atomicAdd(&psum[idx], v);
  }
}

// ---------------------------------------------------------------------------
// Fused: GCN aggregation (+bias) -> LayerNorm -> ReLU -> residual (h bf16)
// Wave-per-node: block = 4 waves = 4 dst nodes; lane owns 4 channels (uint2).
// Neighbor index / dinv are wave-uniform scalar loads; gather is 8B/lane.
// ---------------------------------------------------------------------------
__global__ __launch_bounds__(256) void k_agg_ln(
    const unsigned short* __restrict__ m, unsigned short* __restrict__ h,
    const int* __restrict__ row_ptr, const int* __restrict__ col_idx,
    const float* __restrict__ dinv, const float* __restrict__ bias,
    const float* __restrict__ gamma, const float* __restrict__ beta, int N) {
  int w = threadIdx.x >> 6, l = threadIdx.x & 63;
  int d = blockIdx.x * 4 + w;
  if (d >= N) return;
  int c0 = l * 4;
  float dv = dinv[d];

  // self loop
  uint2 sv = *(const uint2*)&m[(size_t)d * HID + c0];
  float a0 = b2f_lo(sv.x) * dv;
  float a1 = b2f_hi(sv.x) * dv;
  float a2 = b2f_lo(sv.y) * dv;
  float a3 = b2f_hi(sv.y) * dv;

  int beg = row_ptr[d], end = row_ptr[d + 1];
#pragma unroll 4
  for (int jj = beg; jj < end; ++jj) {
    int s = col_idx[jj];            // wave-uniform -> scalar load
    float ws = dinv[s];             // wave-uniform -> scalar load
    uint2 v = *(const uint2*)&m[(size_t)s * HID + c0];
    a0 += ws * b2f_lo(v.x);
    a1 += ws * b2f_hi(v.x);
    a2 += ws * b2f_lo(v.y);
    a3 += ws * b2f_hi(v.y);
  }

  float4 bv = *(const float4*)&bias[c0];
  a0 = a0 * dv + bv.x;
  a1 = a1 * dv + bv.y;
  a2 = a2 * dv + bv.z;
  a3 = a3 * dv + bv.w;

  // wave-level LayerNorm over 256 channels
  float t = a0 + a1 + a2 + a3;
#pragma unroll
  for (int o = 32; o > 0; o >>= 1) t += __shfl_xor(t, o, 64);
  float mu = t * (1.f / 256.f);
  float d0 = a0 - mu, d1 = a1 - mu, d2 = a2 - mu, d3 = a3 - mu;
  float v2 = d0 * d0 + d1 * d1 + d2 * d2 + d3 * d3;
#pragma unroll
  for (int o = 32; o > 0; o >>= 1) v2 += __shfl_xor(v2, o, 64);
  float rs = rsqrtf(v2 * (1.f / 256.f) + LN_EPS);

  float4 gv = *(const float4*)&gamma[c0];
  float4 bt = *(const float4*)&beta[c0];
  uint2 hv = *(const uint2*)&h[(size_t)d * HID + c0];
  float y0 = fmaxf(d0 * rs * gv.x + bt.x, 0.f) + b2f_lo(hv.x);
  float y1 = fmaxf(d1 * rs * gv.y + bt.y, 0.f) + b2f_hi(hv.x);
  float y2 = fmaxf(d2 * rs * gv.z + bt.z, 0.f) + b2f_lo(hv.y);
  float y3 = fmaxf(d3 * rs * gv.w + bt.w, 0.f) + b2f_hi(hv.y);
  uint2 ov;
  ov.x = (unsigned int)f2b(y0) | ((unsigned int)f2b(y1) << 16);
  ov.y = (unsigned int)f2b(y2) | ((unsigned int)f2b(y3) << 16);
  *(uint2*)&h[(size_t)d * HID + c0] = ov;
}

// Final: out[b][c] = psum[b][c] / count(batch==b); counts via binary search.
__global__ void k_final(const float* __restrict__ psum, const int* __restrict__ batch,
                        float* __restrict__ out, int N) {
  int t = threadIdx.x;  // 1024 = 8*128
  int b = t >> 7;
  int lo = 0, hi = N;
  while (lo < hi) { int mid = (lo + hi) >> 1; if (batch[mid] < b) lo = mid + 1; else hi = mid; }
  int lb = lo;
  lo = 0; hi = N;
  while (lo < hi) { int mid = (lo + hi) >> 1; if (batch[mid] <= b) lo = mid + 1; else hi = mid; }
  int cnt = lo - lb;
  out[t] = psum[t] / fmaxf((float)cnt, 1.f);
}

// ---------------------------------------------------------------------------
extern "C" void kernel_launch(void* const* d_in, const int* in_sizes, int n_in,
                              void* d_out, int out_size, void* d_ws, size_t ws_size,
                              hipStream_t stream) {
  const float* x      = (const float*)d_in[0];
  const int*   ei     = (const int*)d_in[1];
  const int*   nt     = (const int*)d_in[2];
  const int*   batch  = (const int*)d_in[3];
  const float* emb    = (const float*)d_in[4];
  const float* W_in   = (const float*)d_in[5];
  const float* b_in   = (const float*)d_in[6];
  const float* Ws     = (const float*)d_in[7];
  const float* bs     = (const float*)d_in[8];
  const float* gammas = (const float*)d_in[9];
  const float* betas  = (const float*)d_in[10];
  const float* W_out  = (const float*)d_in[11];
  const float* b_out  = (const float*)d_in[12];
  float* out = (float*)d_out;

  const int N = in_sizes[2];
  const int E = in_sizes[1] / 2;

  auto align = [](size_t v) { return (v + 255) & ~(size_t)255; };
  char* p = (char*)d_ws;
  unsigned short* h = (unsigned short*)p; p += align((size_t)N * HID * 2);
  unsigned short* m = (unsigned short*)p; p += align((size_t)N * HID * 2);
  unsigned short* pk_in  = (unsigned short*)p; p += align(16 * 5 * 512 * 2);
  unsigned short* pk_sq  = (unsigned short*)p; p += align((size_t)3 * 16 * 8 * 512 * 2);
  unsigned short* pk_out = (unsigned short*)p; p += align(8 * 8 * 512 * 2);
  float* dinv = (float*)p; p += align((size_t)N * 4);
  int* counts = (int*)p;   p += align((size_t)N * 4);
  int* incl   = (int*)p;   p += align((size_t)N * 4);
  int* bsums  = (int*)p;   p += align(64 * 4);
  int* boff   = (int*)p;   p += align(64 * 4);
  int* row_ptr= (int*)p;   p += align((size_t)(N + 1) * 4);
  int* cursor = (int*)p;   p += align((size_t)N * 4);
  int* col_idx= (int*)p;   p += align((size_t)E * 4);
  float* psum = (float*)p; p += align((size_t)NGRAPH * OUTD * 4);

  hipMemsetAsync(counts, 0, (size_t)N * 4, stream);
  hipMemsetAsync(psum, 0, (size_t)NGRAPH * OUTD * 4, stream);

  // weight packing (tiny, one-time per launch)
  {
    int t_in = 16 * 5 * 512;
    k_pack<<<(t_in + 255) / 256, 256, 0, stream>>>(W_in, pk_in, HID, 5, t_in);
    int t_sq = 16 * 8 * 512;
    for (int lyr = 0; lyr < NLAYER; ++lyr)
      k_pack<<<(t_sq + 255) / 256, 256, 0, stream>>>(Ws + (size_t)lyr * HID * HID,
                                                     pk_sq + (size_t)lyr * t_sq, HID, 8, t_sq);
    int t_out = 8 * 8 * 512;
    k_pack<<<(t_out + 255) / 256, 256, 0, stream>>>(W_out, pk_out, OUTD, 8, t_out);
  }

  const int NB = (N + 1023) / 1024;
  k_hist<<<(E + 255) / 256, 256, 0, stream>>>(ei + E, counts, E);
  k_dinv<<<(N + 255) / 256, 256, 0, stream>>>(counts, dinv, N);
  k_scan1<<<NB, 1024, 0, stream>>>(counts, incl, bsums, N);
  k_scan2<<<1, 64, 0, stream>>>(bsums, boff, NB);
  k_scan3<<<NB, 1024, 0, stream>>>(incl, boff, counts, row_ptr, cursor, N);
  k_fill<<<(E + 255) / 256, 256, 0, stream>>>(ei, cursor, col_idx, E);

  const int GB = (N + 63) / 64;
  k_mfma_in<<<GB, 256, 0, stream>>>(x, nt, emb, pk_in, b_in, h, N);

  for (int lyr = 0; lyr < NLAYER; ++lyr) {
    k_mfma_sq<<<GB, 256, 0, stream>>>(h, pk_sq + (size_t)lyr * 16 * 8 * 512, m, N);
    k_agg_ln<<<(N + 3) / 4, 256, 0, stream>>>(m, h, row_ptr, col_idx, dinv,
                                              bs + (size_t)lyr * HID, gammas + (size_t)lyr * HID,
                                              betas + (size_t)lyr * HID, N);
  }

  k_mfma_out_pool<<<GB, 256, 0, stream>>>(h, pk_out, b_out, batch, psum, N);
  k_final<<<1, 1024, 0, stream>>>(psum, batch, out, N);
}

// Round 6
// 517.791 us; speedup vs baseline: 4.1339x; 1.2997x over previous
//
#include <hip/hip_runtime.h>
#include <math.h>

// Problem constants (match reference)
#define HID 256
#define DXIN 128
#define EMBD 32
#define OUTD 128
#define NLAYER 3
#define NGRAPH 8
#define LN_EPS 1e-5f
#define BKP 264   // LDS row stride (bf16 elems): 33 quads, 33%8==1 -> uniform banks
#define NBLK 256  // blocks for edge-binning passes

typedef short s8v __attribute__((ext_vector_type(8)));
typedef float f4v __attribute__((ext_vector_type(4)));

__device__ __forceinline__ float b2f_lo(unsigned int u) {
  return __builtin_bit_cast(float, u << 16);
}
__device__ __forceinline__ float b2f_hi(unsigned int u) {
  return __builtin_bit_cast(float, u & 0xffff0000u);
}
__device__ __forceinline__ unsigned short f2b(float f) {
  unsigned int x = __builtin_bit_cast(unsigned int, f);
  unsigned int lsb = (x >> 16) & 1u;
  x += 0x7fffu + lsb;
  return (unsigned short)(x >> 16);
}

// ---------------------------------------------------------------------------
// CSR build via two-level counting sort (no global data atomics).
// bucket = dst >> 8 (<=256 buckets), dloc = dst & 255.
// ---------------------------------------------------------------------------
// Pass 1: per-block bucket histogram.
__global__ __launch_bounds__(256) void k_b1(const int* __restrict__ dst,
                                            int* __restrict__ blk_cnt, int E, int epb) {
  __shared__ int hist[256];
  int blk = blockIdx.x, tid = threadIdx.x;
  hist[tid] = 0;
  __syncthreads();
  int beg = blk * epb, end = min(E, beg + epb);
  for (int i = beg + tid; i < end; i += 256)
    atomicAdd(&hist[dst[i] >> 8], 1);
  __syncthreads();
  blk_cnt[blk * 256 + tid] = hist[tid];
}

// Pass 2a: bucket totals (column sums of blk_cnt).
__global__ __launch_bounds__(256) void k_bsum(const int* __restrict__ blk_cnt,
                                              int* __restrict__ bucket_cnt) {
  __shared__ int red[4];
  int b = blockIdx.x, tid = threadIdx.x;
  int v = blk_cnt[tid * 256 + b];
#pragma unroll
  for (int o = 32; o > 0; o >>= 1) v += __shfl_xor(v, o, 64);
  if ((tid & 63) == 0) red[tid >> 6] = v;
  __syncthreads();
  if (tid == 0) bucket_cnt[b] = red[0] + red[1] + red[2] + red[3];
}

// Pass 2b: exclusive scan of bucket totals -> bucket_base; tail sentinels.
__global__ __launch_bounds__(256) void k_bscan(const int* __restrict__ bucket_cnt,
                                               int* __restrict__ bucket_base,
                                               int* __restrict__ row_ptr,
                                               int N, int nbuck, int E) {
  __shared__ int s[256];
  int tid = threadIdx.x;
  int v = (tid < nbuck) ? bucket_cnt[tid] : 0;
  s[tid] = v;
  __syncthreads();
  for (int off = 1; off < 256; off <<= 1) {
    int t = (tid >= off) ? s[tid - off] : 0;
    __syncthreads();
    s[tid] += t;
    __syncthreads();
  }
  if (tid < nbuck) bucket_base[tid] = s[tid] - v;
  if (tid == 0) { bucket_base[nbuck] = E; row_ptr[N] = E; }
}

// Pass 2c: per-block write reservations within each bucket.
__global__ __launch_bounds__(256) void k_boff(const int* __restrict__ blk_cnt,
                                              const int* __restrict__ bucket_base,
                                              int* __restrict__ blk_off) {
  __shared__ int s[256];
  int b = blockIdx.x, tid = threadIdx.x;
  int v = blk_cnt[tid * 256 + b];
  s[tid] = v;
  __syncthreads();
  for (int off = 1; off < 256; off <<= 1) {
    int t = (tid >= off) ? s[tid - off] : 0;
    __syncthreads();
    s[tid] += t;
    __syncthreads();
  }
  blk_off[tid * 256 + b] = bucket_base[b] + s[tid] - v;
}

// Pass 3: scatter packed (src | dloc<<16) into disjoint contiguous windows.
__global__ __launch_bounds__(256) void k_b3(const int* __restrict__ ei,
                                            const int* __restrict__ blk_off,
                                            unsigned int* __restrict__ pairs,
                                            int E, int epb) {
  __shared__ int cur[256];
  int blk = blockIdx.x, tid = threadIdx.x;
  cur[tid] = blk_off[blk * 256 + tid];
  __syncthreads();
  int beg = blk * epb, end = min(E, beg + epb);
  for (int i = beg + tid; i < end; i += 256) {
    int s = ei[i];
    int d = ei[E + i];
    int pos = atomicAdd(&cur[d >> 8], 1);
    pairs[pos] = (unsigned int)s | ((unsigned int)(d & 255) << 16);
  }
}

// Pass 4: per-bucket local CSR (LDS atomics only) + row_ptr + dinv + col_idx.
__global__ __launch_bounds__(256) void k_b4(const unsigned int* __restrict__ pairs,
                                            const int* __restrict__ bucket_base,
                                            int* __restrict__ row_ptr,
                                            float* __restrict__ dinv,
                                            int* __restrict__ col_idx, int N) {
  __shared__ int cnt[256];
  __shared__ int s[256];
  int b = blockIdx.x, tid = threadIdx.x;
  int base = bucket_base[b], end = bucket_base[b + 1];
  cnt[tid] = 0;
  __syncthreads();
  for (int i = base + tid; i < end; i += 256)
    atomicAdd(&cnt[pairs[i] >> 16], 1);
  __syncthreads();
  int c = cnt[tid];
  s[tid] = c;
  __syncthreads();
  for (int off = 1; off < 256; off <<= 1) {
    int t = (tid >= off) ? s[tid - off] : 0;
    __syncthreads();
    s[tid] += t;
    __syncthreads();
  }
  int excl = s[tid] - c;
  int d = (b << 8) + tid;
  if (d < N) {
    row_ptr[d] = base + excl;
    dinv[d] = rsqrtf((float)(c + 1));
  }
  __syncthreads();
  cnt[tid] = base + excl;  // reuse as cursor
  __syncthreads();
  for (int i = base + tid; i < end; i += 256) {
    unsigned int w = pairs[i];
    int pos = atomicAdd(&cnt[w >> 16], 1);
    col_idx[pos] = (int)(w & 0xFFFFu);
  }
}

// ---------------------------------------------------------------------------
// Weight pack: W [K][C] fp32 -> bf16 B-fragments.
// ---------------------------------------------------------------------------
__global__ void k_pack(const float* __restrict__ W, unsigned short* __restrict__ dst,
                       int C, int NKS, int total) {
  int t = blockIdx.x * 256 + threadIdx.x;
  if (t >= total) return;
  int j = t & 7;
  int l = (t >> 3) & 63;
  int rest = t >> 9;
  int ks = rest % NKS;
  int ct = rest / NKS;
  int k = ks * 32 + ((l >> 4) << 3) + j;
  int c = ct * 16 + (l & 15);
  dst[t] = f2b(W[(size_t)k * C + c]);
}

// ---------------------------------------------------------------------------
// MFMA GEMM: input projection  h = relu(concat(x, emb[nt]) @ W_in + b_in)
// ---------------------------------------------------------------------------
__global__ __launch_bounds__(256) void k_mfma_in(
    const float* __restrict__ x, const int* __restrict__ nt, const float* __restrict__ emb,
    const unsigned short* __restrict__ Wpk, const float* __restrict__ bias,
    unsigned short* __restrict__ h, int N) {
  __shared__ unsigned short a_lds[64 * BKP];
  int tid = threadIdx.x;
  int w = tid >> 6, l = tid & 63;
  int row0 = blockIdx.x * 64;

  for (int i = 0; i < 4; ++i) {
    int cc = i * 256 + tid;
    int r = cc >> 4, ch = cc & 15;
    int row = row0 + r;
    unsigned short tmp[8];
    if (row < N) {
      const float* xr = &x[(size_t)row * DXIN + ch * 8];
      float4 v0 = *(const float4*)xr;
      float4 v1 = *(const float4*)(xr + 4);
      tmp[0] = f2b(v0.x); tmp[1] = f2b(v0.y); tmp[2] = f2b(v0.z); tmp[3] = f2b(v0.w);
      tmp[4] = f2b(v1.x); tmp[5] = f2b(v1.y); tmp[6] = f2b(v1.z); tmp[7] = f2b(v1.w);
    } else {
      for (int q = 0; q < 8; ++q) tmp[q] = 0;
    }
    *(uint4*)&a_lds[r * BKP + ch * 8] = *(const uint4*)tmp;
  }
  {
    int r = tid >> 2, ch = tid & 3;
    int row = row0 + r;
    unsigned short tmp[8];
    if (row < N) {
      int typ = nt[row];
      const float* er = &emb[typ * EMBD + ch * 8];
      float4 v0 = *(const float4*)er;
      float4 v1 = *(const float4*)(er + 4);
      tmp[0] = f2b(v0.x); tmp[1] = f2b(v0.y); tmp[2] = f2b(v0.z); tmp[3] = f2b(v0.w);
      tmp[4] = f2b(v1.x); tmp[5] = f2b(v1.y); tmp[6] = f2b(v1.z); tmp[7] = f2b(v1.w);
    } else {
      for (int q = 0; q < 8; ++q) tmp[q] = 0;
    }
    *(uint4*)&a_lds[r * BKP + DXIN + ch * 8] = *(const uint4*)tmp;
  }
  __syncthreads();

  f4v acc[4][4];
#pragma unroll
  for (int rt = 0; rt < 4; ++rt)
#pragma unroll
    for (int ct = 0; ct < 4; ++ct) acc[rt][ct] = (f4v)0.f;

  for (int ks = 0; ks < 5; ++ks) {
    s8v af[4];
#pragma unroll
    for (int rt = 0; rt < 4; ++rt)
      af[rt] = *(const s8v*)&a_lds[(rt * 16 + (l & 15)) * BKP + ks * 32 + (l >> 4) * 8];
#pragma unroll
    for (int ct = 0; ct < 4; ++ct) {
      s8v bf = *(const s8v*)&Wpk[(size_t)(((w * 4 + ct) * 5 + ks) * 64 + l) * 8];
#pragma unroll
      for (int rt = 0; rt < 4; ++rt)
        acc[rt][ct] = __builtin_amdgcn_mfma_f32_16x16x32_bf16(af[rt], bf, acc[rt][ct], 0, 0, 0);
    }
  }
  __syncthreads();

#pragma unroll
  for (int rt = 0; rt < 4; ++rt)
#pragma unroll
    for (int ct = 0; ct < 4; ++ct) {
      int col = w * 64 + ct * 16 + (l & 15);
      float bv = bias[col];
#pragma unroll
      for (int reg = 0; reg < 4; ++reg) {
        int r = rt * 16 + (l >> 4) * 4 + reg;
        a_lds[r * BKP + col] = f2b(fmaxf(acc[rt][ct][reg] + bv, 0.f));
      }
    }
  __syncthreads();
  for (int i = 0; i < 8; ++i) {
    int cc = i * 256 + tid;
    int r = cc >> 5, ch = cc & 31;
    int row = row0 + r;
    if (row < N)
      *(uint4*)&h[(size_t)row * HID + ch * 8] = *(const uint4*)&a_lds[r * BKP + ch * 8];
  }
}

// ---------------------------------------------------------------------------
// MFMA GEMM: square layer  m = h @ W  (bf16 in/out, K=256)
// ---------------------------------------------------------------------------
__global__ __launch_bounds__(256) void k_mfma_sq(
    const unsigned short* __restrict__ A, const unsigned short* __restrict__ Wpk,
    unsigned short* __restrict__ Mout, int N) {
  __shared__ unsigned short a_lds[64 * BKP];
  int tid = threadIdx.x;
  int w = tid >> 6, l = tid & 63;
  int row0 = blockIdx.x * 64;

  for (int i = 0; i < 8; ++i) {
    int cc = i * 256 + tid;
    int r = cc >> 5, ch = cc & 31;
    int row = row0 + r;
    uint4 v = make_uint4(0u, 0u, 0u, 0u);
    if (row < N) v = *(const uint4*)&A[(size_t)row * HID + ch * 8];
    *(uint4*)&a_lds[r * BKP + ch * 8] = v;
  }
  __syncthreads();

  f4v acc[4][4];
#pragma unroll
  for (int rt = 0; rt < 4; ++rt)
#pragma unroll
    for (int ct = 0; ct < 4; ++ct) acc[rt][ct] = (f4v)0.f;

  for (int ks = 0; ks < 8; ++ks) {
    s8v af[4];
#pragma unroll
    for (int rt = 0; rt < 4; ++rt)
      af[rt] = *(const s8v*)&a_lds[(rt * 16 + (l & 15)) * BKP + ks * 32 + (l >> 4) * 8];
#pragma unroll
    for (int ct = 0; ct < 4; ++ct) {
      s8v bf = *(const s8v*)&Wpk[(size_t)(((w * 4 + ct) * 8 + ks) * 64 + l) * 8];
#pragma unroll
      for (int rt = 0; rt < 4; ++rt)
        acc[rt][ct] = __builtin_amdgcn_mfma_f32_16x16x32_bf16(af[rt], bf, acc[rt][ct], 0, 0, 0);
    }
  }
  __syncthreads();

#pragma unroll
  for (int rt = 0; rt < 4; ++rt)
#pragma unroll
    for (int ct = 0; ct < 4; ++ct) {
      int col = w * 64 + ct * 16 + (l & 15);
#pragma unroll
      for (int reg = 0; reg < 4; ++reg) {
        int r = rt * 16 + (l >> 4) * 4 + reg;
        a_lds[r * BKP + col] = f2b(acc[rt][ct][reg]);
      }
    }
  __syncthreads();
  for (int i = 0; i < 8; ++i) {
    int cc = i * 256 + tid;
    int r = cc >> 5, ch = cc & 31;
    int row = row0 + r;
    if (row < N)
      *(uint4*)&Mout[(size_t)row * HID + ch * 8] = *(const uint4*)&a_lds[r * BKP + ch * 8];
  }
}

// ---------------------------------------------------------------------------
// MFMA GEMM: output layer (C=128) + bias + mean-pool partials via LDS bins.
// ---------------------------------------------------------------------------
__global__ __launch_bounds__(256) void k_mfma_out_pool(
    const unsigned short* __restrict__ A, const unsigned short* __restrict__ Wpk,
    const float* __restrict__ bias, const int* __restrict__ batch,
    float* __restrict__ psum, int N) {
  __shared__ unsigned short a_lds[64 * BKP];
  __shared__ float pool[NGRAPH * OUTD];
  __shared__ int b_s[64];
  int tid = threadIdx.x;
  int w = tid >> 6, l = tid & 63;
  int row0 = blockIdx.x * 64;

#pragma unroll
  for (int i = 0; i < 4; ++i) pool[tid * 4 + i] = 0.f;
  if (tid < 64) b_s[tid] = (row0 + tid < N) ? batch[row0 + tid] : -1;

  for (int i = 0; i < 8; ++i) {
    int cc = i * 256 + tid;
    int r = cc >> 5, ch = cc & 31;
    int row = row0 + r;
    uint4 v = make_uint4(0u, 0u, 0u, 0u);
    if (row < N) v = *(const uint4*)&A[(size_t)row * HID + ch * 8];
    *(uint4*)&a_lds[r * BKP + ch * 8] = v;
  }
  __syncthreads();

  f4v acc[4][2];
#pragma unroll
  for (int rt = 0; rt < 4; ++rt)
#pragma unroll
    for (int ct = 0; ct < 2; ++ct) acc[rt][ct] = (f4v)0.f;

  for (int ks = 0; ks < 8; ++ks) {
    s8v af[4];
#pragma unroll
    for (int rt = 0; rt < 4; ++rt)
      af[rt] = *(const s8v*)&a_lds[(rt * 16 + (l & 15)) * BKP + ks * 32 + (l >> 4) * 8];
#pragma unroll
    for (int ct = 0; ct < 2; ++ct) {
      s8v bf = *(const s8v*)&Wpk[(size_t)(((w * 2 + ct) * 8 + ks) * 64 + l) * 8];
#pragma unroll
      for (int rt = 0; rt < 4; ++rt)
        acc[rt][ct] = __builtin_amdgcn_mfma_f32_16x16x32_bf16(af[rt], bf, acc[rt][ct], 0, 0, 0);
    }
  }

#pragma unroll
  for (int ct = 0; ct < 2; ++ct) {
    int col = w * 32 + ct * 16 + (l & 15);
    float bv = bias[col];
    float run = 0.f;
    int cur = -1;
#pragma unroll
    for (int rt = 0; rt < 4; ++rt)
#pragma unroll
      for (int reg = 0; reg < 4; ++reg) {
        int rrel = rt * 16 + (l >> 4) * 4 + reg;
        int g = b_s[rrel];
        if (g != cur) {
          if (cur >= 0) atomicAdd(&pool[cur * OUTD + col], run);
          run = 0.f;
          cur = g;
        }
        if (g >= 0) run += acc[rt][ct][reg] + bv;
      }
    if (cur >= 0) atomicAdd(&pool[cur * OUTD + col], run);
  }
  __syncthreads();
#pragma unroll
  for (int i = 0; i < 4; ++i) {
    int idx = tid * 4 + i;
    float v = pool[idx];
    if (v != 0.f) atomicAdd(&psum[idx], v);
  }
}

// ---------------------------------------------------------------------------
// Fused: GCN aggregation (+bias) -> LayerNorm -> ReLU -> residual (h bf16)
// Wave-per-node; lane owns 4 channels (one uint2 gather per neighbor).
// ---------------------------------------------------------------------------
__global__ __launch_bounds__(256) void k_agg_ln(
    const unsigned short* __restrict__ m, unsigned short* __restrict__ h,
    const int* __restrict__ row_ptr, const int* __restrict__ col_idx,
    const float* __restrict__ dinv, const float* __restrict__ bias,
    const float* __restrict__ gamma, const float* __restrict__ beta, int N) {
  int w = threadIdx.x >> 6, l = threadIdx.x & 63;
  int d = blockIdx.x * 4 + w;
  if (d >= N) return;
  int c0 = l * 4;
  float dv = dinv[d];

  uint2 sv = *(const uint2*)&m[(size_t)d * HID + c0];
  float a0 = b2f_lo(sv.x) * dv;
  float a1 = b2f_hi(sv.x) * dv;
  float a2 = b2f_lo(sv.y) * dv;
  float a3 = b2f_hi(sv.y) * dv;

  int beg = row_ptr[d], end = row_ptr[d + 1];
#pragma unroll 4
  for (int jj = beg; jj < end; ++jj) {
    int s = col_idx[jj];
    float ws = dinv[s];
    uint2 v = *(const uint2*)&m[(size_t)s * HID + c0];
    a0 += ws * b2f_lo(v.x);
    a1 += ws * b2f_hi(v.x);
    a2 += ws * b2f_lo(v.y);
    a3 += ws * b2f_hi(v.y);
  }

  float4 bv = *(const float4*)&bias[c0];
  a0 = a0 * dv + bv.x;
  a1 = a1 * dv + bv.y;
  a2 = a2 * dv + bv.z;
  a3 = a3 * dv + bv.w;

  float t = a0 + a1 + a2 + a3;
#pragma unroll
  for (int o = 32; o > 0; o >>= 1) t += __shfl_xor(t, o, 64);
  float mu = t * (1.f / 256.f);
  float d0 = a0 - mu, d1 = a1 - mu, d2 = a2 - mu, d3 = a3 - mu;
  float v2 = d0 * d0 + d1 * d1 + d2 * d2 + d3 * d3;
#pragma unroll
  for (int o = 32; o > 0; o >>= 1) v2 += __shfl_xor(v2, o, 64);
  float rs = rsqrtf(v2 * (1.f / 256.f) + LN_EPS);

  float4 gv = *(const float4*)&gamma[c0];
  float4 bt = *(const float4*)&beta[c0];
  uint2 hv = *(const uint2*)&h[(size_t)d * HID + c0];
  float y0 = fmaxf(d0 * rs * gv.x + bt.x, 0.f) + b2f_lo(hv.x);
  float y1 = fmaxf(d1 * rs * gv.y + bt.y, 0.f) + b2f_hi(hv.x);
  float y2 = fmaxf(d2 * rs * gv.z + bt.z, 0.f) + b2f_lo(hv.y);
  float y3 = fmaxf(d3 * rs * gv.w + bt.w, 0.f) + b2f_hi(hv.y);
  uint2 ov;
  ov.x = (unsigned int)f2b(y0) | ((unsigned int)f2b(y1) << 16);
  ov.y = (unsigned int)f2b(y2) | ((unsigned int)f2b(y3) << 16);
  *(uint2*)&h[(size_t)d * HID + c0] = ov;
}

// Final: out[b][c] = psum[b][c] / count(batch==b); counts via binary search.
__global__ void k_final(const float* __restrict__ psum, const int* __restrict__ batch,
                        float* __restrict__ out, int N) {
  int t = threadIdx.x;  // 1024 = 8*128
  int b = t >> 7;
  int lo = 0, hi = N;
  while (lo < hi) { int mid = (lo + hi) >> 1; if (batch[mid] < b) lo = mid + 1; else hi = mid; }
  int lb = lo;
  lo = 0; hi = N;
  while (lo < hi) { int mid = (lo + hi) >> 1; if (batch[mid] <= b) lo = mid + 1; else hi = mid; }
  int cnt = lo - lb;
  out[t] = psum[t] / fmaxf((float)cnt, 1.f);
}

// ---------------------------------------------------------------------------
extern "C" void kernel_launch(void* const* d_in, const int* in_sizes, int n_in,
                              void* d_out, int out_size, void* d_ws, size_t ws_size,
                              hipStream_t stream) {
  const float* x      = (const float*)d_in[0];
  const int*   ei     = (const int*)d_in[1];
  const int*   nt     = (const int*)d_in[2];
  const int*   batch  = (const int*)d_in[3];
  const float* emb    = (const float*)d_in[4];
  const float* W_in   = (const float*)d_in[5];
  const float* b_in   = (const float*)d_in[6];
  const float* Ws     = (const float*)d_in[7];
  const float* bs     = (const float*)d_in[8];
  const float* gammas = (const float*)d_in[9];
  const float* betas  = (const float*)d_in[10];
  const float* W_out  = (const float*)d_in[11];
  const float* b_out  = (const float*)d_in[12];
  float* out = (float*)d_out;

  const int N = in_sizes[2];
  const int E = in_sizes[1] / 2;
  const int nbuck = (N + 255) >> 8;
  const int epb = (E + NBLK - 1) / NBLK;

  auto align = [](size_t v) { return (v + 255) & ~(size_t)255; };
  char* p = (char*)d_ws;
  unsigned short* h = (unsigned short*)p; p += align((size_t)N * HID * 2);
  unsigned short* m = (unsigned short*)p; p += align((size_t)N * HID * 2);
  unsigned short* pk_in  = (unsigned short*)p; p += align(16 * 5 * 512 * 2);
  unsigned short* pk_sq  = (unsigned short*)p; p += align((size_t)3 * 16 * 8 * 512 * 2);
  unsigned short* pk_out = (unsigned short*)p; p += align(8 * 8 * 512 * 2);
  float* dinv = (float*)p;        p += align((size_t)N * 4);
  int* row_ptr = (int*)p;         p += align((size_t)(N + 1) * 4);
  int* col_idx = (int*)p;         p += align((size_t)E * 4);
  unsigned int* pairs = (unsigned int*)p; p += align((size_t)E * 4);
  int* blk_cnt = (int*)p;         p += align((size_t)NBLK * 256 * 4);
  int* blk_off = (int*)p;         p += align((size_t)NBLK * 256 * 4);
  int* bucket_cnt = (int*)p;      p += align(256 * 4);
  int* bucket_base = (int*)p;     p += align(257 * 4);
  float* psum = (float*)p;        p += align((size_t)NGRAPH * OUTD * 4);

  hipMemsetAsync(psum, 0, (size_t)NGRAPH * OUTD * 4, stream);

  // weight packing (tiny, one-time per launch)
  {
    int t_in = 16 * 5 * 512;
    k_pack<<<(t_in + 255) / 256, 256, 0, stream>>>(W_in, pk_in, HID, 5, t_in);
    int t_sq = 16 * 8 * 512;
    for (int lyr = 0; lyr < NLAYER; ++lyr)
      k_pack<<<(t_sq + 255) / 256, 256, 0, stream>>>(Ws + (size_t)lyr * HID * HID,
                                                     pk_sq + (size_t)lyr * t_sq, HID, 8, t_sq);
    int t_out = 8 * 8 * 512;
    k_pack<<<(t_out + 255) / 256, 256, 0, stream>>>(W_out, pk_out, OUTD, 8, t_out);
  }

  // CSR build (two-level counting sort, no global data atomics)
  k_b1<<<NBLK, 256, 0, stream>>>(ei + E, blk_cnt, E, epb);
  k_bsum<<<nbuck, 256, 0, stream>>>(blk_cnt, bucket_cnt);
  k_bscan<<<1, 256, 0, stream>>>(bucket_cnt, bucket_base, row_ptr, N, nbuck, E);
  k_boff<<<nbuck, 256, 0, stream>>>(blk_cnt, bucket_base, blk_off);
  k_b3<<<NBLK, 256, 0, stream>>>(ei, blk_off, pairs, E, epb);
  k_b4<<<nbuck, 256, 0, stream>>>(pairs, bucket_base, row_ptr, dinv, col_idx, N);

  const int GB = (N + 63) / 64;
  k_mfma_in<<<GB, 256, 0, stream>>>(x, nt, emb, pk_in, b_in, h, N);

  for (int lyr = 0; lyr < NLAYER; ++lyr) {
    k_mfma_sq<<<GB, 256, 0, stream>>>(h, pk_sq + (size_t)lyr * 16 * 8 * 512, m, N);
    k_agg_ln<<<(N + 3) / 4, 256, 0, stream>>>(m, h, row_ptr, col_idx, dinv,
                                              bs + (size_t)lyr * HID, gammas + (size_t)lyr * HID,
                                              betas + (size_t)lyr * HID, N);
  }

  k_mfma_out_pool<<<GB, 256, 0, stream>>>(h, pk_out, b_out, batch, psum, N);
  k_final<<<1, 1024, 0, stream>>>(psum, batch, out, N);
}

// Round 7
// 392.225 us; speedup vs baseline: 5.4573x; 1.3201x over previous
//
#include <hip/hip_runtime.h>
#include <math.h>

// Problem constants (match reference)
#define HID 256
#define DXIN 128
#define EMBD 32
#define OUTD 128
#define NLAYER 3
#define NGRAPH 8
#define LN_EPS 1e-5f
#define BKP 264   // LDS row stride (bf16 elems): 33 quads, 33%8==1 -> uniform banks
#define NBLK 256  // blocks for edge-binning passes

typedef short s8v __attribute__((ext_vector_type(8)));
typedef float f4v __attribute__((ext_vector_type(4)));
typedef float f2v __attribute__((ext_vector_type(2)));

__device__ __forceinline__ float b2f_lo(unsigned int u) {
  return __builtin_bit_cast(float, u << 16);
}
__device__ __forceinline__ float b2f_hi(unsigned int u) {
  return __builtin_bit_cast(float, u & 0xffff0000u);
}
__device__ __forceinline__ unsigned short f2b(float f) {
  unsigned int x = __builtin_bit_cast(unsigned int, f);
  unsigned int lsb = (x >> 16) & 1u;
  x += 0x7fffu + lsb;
  return (unsigned short)(x >> 16);
}

// ---------------------------------------------------------------------------
// CSR build via two-level counting sort (no global data atomics).
// bucket = dst >> 8 (<=256 buckets), dloc = dst & 255.
// ---------------------------------------------------------------------------
__global__ __launch_bounds__(256) void k_b1(const int* __restrict__ dst,
                                            int* __restrict__ blk_cnt, int E, int epb) {
  __shared__ int hist[256];
  int blk = blockIdx.x, tid = threadIdx.x;
  hist[tid] = 0;
  __syncthreads();
  int beg = blk * epb, end = min(E, beg + epb);
  for (int i = beg + tid; i < end; i += 256)
    atomicAdd(&hist[dst[i] >> 8], 1);
  __syncthreads();
  blk_cnt[blk * 256 + tid] = hist[tid];
}

__global__ __launch_bounds__(256) void k_bsum(const int* __restrict__ blk_cnt,
                                              int* __restrict__ bucket_cnt) {
  __shared__ int red[4];
  int b = blockIdx.x, tid = threadIdx.x;
  int v = blk_cnt[tid * 256 + b];
#pragma unroll
  for (int o = 32; o > 0; o >>= 1) v += __shfl_xor(v, o, 64);
  if ((tid & 63) == 0) red[tid >> 6] = v;
  __syncthreads();
  if (tid == 0) bucket_cnt[b] = red[0] + red[1] + red[2] + red[3];
}

__global__ __launch_bounds__(256) void k_bscan(const int* __restrict__ bucket_cnt,
                                               int* __restrict__ bucket_base,
                                               int* __restrict__ row_ptr,
                                               int N, int nbuck, int E) {
  __shared__ int s[256];
  int tid = threadIdx.x;
  int v = (tid < nbuck) ? bucket_cnt[tid] : 0;
  s[tid] = v;
  __syncthreads();
  for (int off = 1; off < 256; off <<= 1) {
    int t = (tid >= off) ? s[tid - off] : 0;
    __syncthreads();
    s[tid] += t;
    __syncthreads();
  }
  if (tid < nbuck) bucket_base[tid] = s[tid] - v;
  if (tid == 0) { bucket_base[nbuck] = E; row_ptr[N] = E; }
}

__global__ __launch_bounds__(256) void k_boff(const int* __restrict__ blk_cnt,
                                              const int* __restrict__ bucket_base,
                                              int* __restrict__ blk_off) {
  __shared__ int s[256];
  int b = blockIdx.x, tid = threadIdx.x;
  int v = blk_cnt[tid * 256 + b];
  s[tid] = v;
  __syncthreads();
  for (int off = 1; off < 256; off <<= 1) {
    int t = (tid >= off) ? s[tid - off] : 0;
    __syncthreads();
    s[tid] += t;
    __syncthreads();
  }
  blk_off[tid * 256 + b] = bucket_base[b] + s[tid] - v;
}

__global__ __launch_bounds__(256) void k_b3(const int* __restrict__ ei,
                                            const int* __restrict__ blk_off,
                                            unsigned int* __restrict__ pairs,
                                            int E, int epb) {
  __shared__ int cur[256];
  int blk = blockIdx.x, tid = threadIdx.x;
  cur[tid] = blk_off[blk * 256 + tid];
  __syncthreads();
  int beg = blk * epb, end = min(E, beg + epb);
  for (int i = beg + tid; i < end; i += 256) {
    int s = ei[i];
    int d = ei[E + i];
    int pos = atomicAdd(&cur[d >> 8], 1);
    pairs[pos] = (unsigned int)s | ((unsigned int)(d & 255) << 16);
  }
}

__global__ __launch_bounds__(256) void k_b4(const unsigned int* __restrict__ pairs,
                                            const int* __restrict__ bucket_base,
                                            int* __restrict__ row_ptr,
                                            float* __restrict__ dinv,
                                            int* __restrict__ col_idx, int N) {
  __shared__ int cnt[256];
  __shared__ int s[256];
  int b = blockIdx.x, tid = threadIdx.x;
  int base = bucket_base[b], end = bucket_base[b + 1];
  cnt[tid] = 0;
  __syncthreads();
  for (int i = base + tid; i < end; i += 256)
    atomicAdd(&cnt[pairs[i] >> 16], 1);
  __syncthreads();
  int c = cnt[tid];
  s[tid] = c;
  __syncthreads();
  for (int off = 1; off < 256; off <<= 1) {
    int t = (tid >= off) ? s[tid - off] : 0;
    __syncthreads();
    s[tid] += t;
    __syncthreads();
  }
  int excl = s[tid] - c;
  int d = (b << 8) + tid;
  if (d < N) {
    row_ptr[d] = base + excl;
    dinv[d] = rsqrtf((float)(c + 1));
  }
  __syncthreads();
  cnt[tid] = base + excl;  // reuse as cursor
  __syncthreads();
  for (int i = base + tid; i < end; i += 256) {
    unsigned int w = pairs[i];
    int pos = atomicAdd(&cnt[w >> 16], 1);
    col_idx[pos] = (int)(w & 0xFFFFu);
  }
}

// ---------------------------------------------------------------------------
// Weight pack: W [K][C] fp32 -> bf16 B-fragments.
// ---------------------------------------------------------------------------
__global__ void k_pack(const float* __restrict__ W, unsigned short* __restrict__ dst,
                       int C, int NKS, int total) {
  int t = blockIdx.x * 256 + threadIdx.x;
  if (t >= total) return;
  int j = t & 7;
  int l = (t >> 3) & 63;
  int rest = t >> 9;
  int ks = rest % NKS;
  int ct = rest / NKS;
  int k = ks * 32 + ((l >> 4) << 3) + j;
  int c = ct * 16 + (l & 15);
  dst[t] = f2b(W[(size_t)k * C + c]);
}

// ---------------------------------------------------------------------------
// MFMA GEMM: input projection  h = relu(concat(x, emb[nt]) @ W_in + b_in)
// ---------------------------------------------------------------------------
__global__ __launch_bounds__(256) void k_mfma_in(
    const float* __restrict__ x, const int* __restrict__ nt, const float* __restrict__ emb,
    const unsigned short* __restrict__ Wpk, const float* __restrict__ bias,
    unsigned short* __restrict__ h, int N) {
  __shared__ unsigned short a_lds[64 * BKP];
  int tid = threadIdx.x;
  int w = tid >> 6, l = tid & 63;
  int row0 = blockIdx.x * 64;

  for (int i = 0; i < 4; ++i) {
    int cc = i * 256 + tid;
    int r = cc >> 4, ch = cc & 15;
    int row = row0 + r;
    unsigned short tmp[8];
    if (row < N) {
      const float* xr = &x[(size_t)row * DXIN + ch * 8];
      float4 v0 = *(const float4*)xr;
      float4 v1 = *(const float4*)(xr + 4);
      tmp[0] = f2b(v0.x); tmp[1] = f2b(v0.y); tmp[2] = f2b(v0.z); tmp[3] = f2b(v0.w);
      tmp[4] = f2b(v1.x); tmp[5] = f2b(v1.y); tmp[6] = f2b(v1.z); tmp[7] = f2b(v1.w);
    } else {
      for (int q = 0; q < 8; ++q) tmp[q] = 0;
    }
    *(uint4*)&a_lds[r * BKP + ch * 8] = *(const uint4*)tmp;
  }
  {
    int r = tid >> 2, ch = tid & 3;
    int row = row0 + r;
    unsigned short tmp[8];
    if (row < N) {
      int typ = nt[row];
      const float* er = &emb[typ * EMBD + ch * 8];
      float4 v0 = *(const float4*)er;
      float4 v1 = *(const float4*)(er + 4);
      tmp[0] = f2b(v0.x); tmp[1] = f2b(v0.y); tmp[2] = f2b(v0.z); tmp[3] = f2b(v0.w);
      tmp[4] = f2b(v1.x); tmp[5] = f2b(v1.y); tmp[6] = f2b(v1.z); tmp[7] = f2b(v1.w);
    } else {
      for (int q = 0; q < 8; ++q) tmp[q] = 0;
    }
    *(uint4*)&a_lds[r * BKP + DXIN + ch * 8] = *(const uint4*)tmp;
  }
  __syncthreads();

  f4v acc[4][4];
#pragma unroll
  for (int rt = 0; rt < 4; ++rt)
#pragma unroll
    for (int ct = 0; ct < 4; ++ct) acc[rt][ct] = (f4v)0.f;

  for (int ks = 0; ks < 5; ++ks) {
    s8v af[4];
#pragma unroll
    for (int rt = 0; rt < 4; ++rt)
      af[rt] = *(const s8v*)&a_lds[(rt * 16 + (l & 15)) * BKP + ks * 32 + (l >> 4) * 8];
#pragma unroll
    for (int ct = 0; ct < 4; ++ct) {
      s8v bf = *(const s8v*)&Wpk[(size_t)(((w * 4 + ct) * 5 + ks) * 64 + l) * 8];
#pragma unroll
      for (int rt = 0; rt < 4; ++rt)
        acc[rt][ct] = __builtin_amdgcn_mfma_f32_16x16x32_bf16(af[rt], bf, acc[rt][ct], 0, 0, 0);
    }
  }
  __syncthreads();

#pragma unroll
  for (int rt = 0; rt < 4; ++rt)
#pragma unroll
    for (int ct = 0; ct < 4; ++ct) {
      int col = w * 64 + ct * 16 + (l & 15);
      float bv = bias[col];
#pragma unroll
      for (int reg = 0; reg < 4; ++reg) {
        int r = rt * 16 + (l >> 4) * 4 + reg;
        a_lds[r * BKP + col] = f2b(fmaxf(acc[rt][ct][reg] + bv, 0.f));
      }
    }
  __syncthreads();
  for (int i = 0; i < 8; ++i) {
    int cc = i * 256 + tid;
    int r = cc >> 5, ch = cc & 31;
    int row = row0 + r;
    if (row < N)
      *(uint4*)&h[(size_t)row * HID + ch * 8] = *(const uint4*)&a_lds[r * BKP + ch * 8];
  }
}

// ---------------------------------------------------------------------------
// MFMA GEMM: square layer  m8 = fp8(h @ W)  (bf16 in, fp8 e4m3 out, K=256)
// ---------------------------------------------------------------------------
__global__ __launch_bounds__(256) void k_mfma_sq(
    const unsigned short* __restrict__ A, const unsigned short* __restrict__ Wpk,
    unsigned char* __restrict__ m8, int N) {
  __shared__ unsigned short a_lds[64 * BKP];
  int tid = threadIdx.x;
  int w = tid >> 6, l = tid & 63;
  int row0 = blockIdx.x * 64;

  for (int i = 0; i < 8; ++i) {
    int cc = i * 256 + tid;
    int r = cc >> 5, ch = cc & 31;
    int row = row0 + r;
    uint4 v = make_uint4(0u, 0u, 0u, 0u);
    if (row < N) v = *(const uint4*)&A[(size_t)row * HID + ch * 8];
    *(uint4*)&a_lds[r * BKP + ch * 8] = v;
  }
  __syncthreads();

  f4v acc[4][4];
#pragma unroll
  for (int rt = 0; rt < 4; ++rt)
#pragma unroll
    for (int ct = 0; ct < 4; ++ct) acc[rt][ct] = (f4v)0.f;

  for (int ks = 0; ks < 8; ++ks) {
    s8v af[4];
#pragma unroll
    for (int rt = 0; rt < 4; ++rt)
      af[rt] = *(const s8v*)&a_lds[(rt * 16 + (l & 15)) * BKP + ks * 32 + (l >> 4) * 8];
#pragma unroll
    for (int ct = 0; ct < 4; ++ct) {
      s8v bf = *(const s8v*)&Wpk[(size_t)(((w * 4 + ct) * 8 + ks) * 64 + l) * 8];
#pragma unroll
      for (int rt = 0; rt < 4; ++rt)
        acc[rt][ct] = __builtin_amdgcn_mfma_f32_16x16x32_bf16(af[rt], bf, acc[rt][ct], 0, 0, 0);
    }
  }
  __syncthreads();

  // transpose via LDS (bf16), then convert to fp8 on the coalesced store
#pragma unroll
  for (int rt = 0; rt < 4; ++rt)
#pragma unroll
    for (int ct = 0; ct < 4; ++ct) {
      int col = w * 64 + ct * 16 + (l & 15);
#pragma unroll
      for (int reg = 0; reg < 4; ++reg) {
        int r = rt * 16 + (l >> 4) * 4 + reg;
        a_lds[r * BKP + col] = f2b(acc[rt][ct][reg]);
      }
    }
  __syncthreads();
  for (int i = 0; i < 8; ++i) {
    int cc = i * 256 + tid;
    int r = cc >> 5, ch = cc & 31;
    int row = row0 + r;
    if (row < N) {
      uint4 v = *(const uint4*)&a_lds[r * BKP + ch * 8];
      float f0 = b2f_lo(v.x), f1 = b2f_hi(v.x);
      float f2 = b2f_lo(v.y), f3 = b2f_hi(v.y);
      float f4 = b2f_lo(v.z), f5 = b2f_hi(v.z);
      float f6 = b2f_lo(v.w), f7 = b2f_hi(v.w);
      unsigned int p0 = 0, p1 = 0;
      p0 = __builtin_amdgcn_cvt_pk_fp8_f32(f0, f1, p0, 0);
      p0 = __builtin_amdgcn_cvt_pk_fp8_f32(f2, f3, p0, 1);
      p1 = __builtin_amdgcn_cvt_pk_fp8_f32(f4, f5, p1, 0);
      p1 = __builtin_amdgcn_cvt_pk_fp8_f32(f6, f7, p1, 1);
      *(uint2*)&m8[(size_t)row * HID + ch * 8] = make_uint2(p0, p1);
    }
  }
}

// ---------------------------------------------------------------------------
// MFMA GEMM: output layer (C=128) + bias + mean-pool partials via LDS bins.
// ---------------------------------------------------------------------------
__global__ __launch_bounds__(256) void k_mfma_out_pool(
    const unsigned short* __restrict__ A, const unsigned short* __restrict__ Wpk,
    const float* __restrict__ bias, const int* __restrict__ batch,
    float* __restrict__ psum, int N) {
  __shared__ unsigned short a_lds[64 * BKP];
  __shared__ float pool[NGRAPH * OUTD];
  __shared__ int b_s[64];
  int tid = threadIdx.x;
  int w = tid >> 6, l = tid & 63;
  int row0 = blockIdx.x * 64;

#pragma unroll
  for (int i = 0; i < 4; ++i) pool[tid * 4 + i] = 0.f;
  if (tid < 64) b_s[tid] = (row0 + tid < N) ? batch[row0 + tid] : -1;

  for (int i = 0; i < 8; ++i) {
    int cc = i * 256 + tid;
    int r = cc >> 5, ch = cc & 31;
    int row = row0 + r;
    uint4 v = make_uint4(0u, 0u, 0u, 0u);
    if (row < N) v = *(const uint4*)&A[(size_t)row * HID + ch * 8];
    *(uint4*)&a_lds[r * BKP + ch * 8] = v;
  }
  __syncthreads();

  f4v acc[4][2];
#pragma unroll
  for (int rt = 0; rt < 4; ++rt)
#pragma unroll
    for (int ct = 0; ct < 2; ++ct) acc[rt][ct] = (f4v)0.f;

  for (int ks = 0; ks < 8; ++ks) {
    s8v af[4];
#pragma unroll
    for (int rt = 0; rt < 4; ++rt)
      af[rt] = *(const s8v*)&a_lds[(rt * 16 + (l & 15)) * BKP + ks * 32 + (l >> 4) * 8];
#pragma unroll
    for (int ct = 0; ct < 2; ++ct) {
      s8v bf = *(const s8v*)&Wpk[(size_t)(((w * 2 + ct) * 8 + ks) * 64 + l) * 8];
#pragma unroll
      for (int rt = 0; rt < 4; ++rt)
        acc[rt][ct] = __builtin_amdgcn_mfma_f32_16x16x32_bf16(af[rt], bf, acc[rt][ct], 0, 0, 0);
    }
  }

#pragma unroll
  for (int ct = 0; ct < 2; ++ct) {
    int col = w * 32 + ct * 16 + (l & 15);
    float bv = bias[col];
    float run = 0.f;
    int cur = -1;
#pragma unroll
    for (int rt = 0; rt < 4; ++rt)
#pragma unroll
      for (int reg = 0; reg < 4; ++reg) {
        int rrel = rt * 16 + (l >> 4) * 4 + reg;
        int g = b_s[rrel];
        if (g != cur) {
          if (cur >= 0) atomicAdd(&pool[cur * OUTD + col], run);
          run = 0.f;
          cur = g;
        }
        if (g >= 0) run += acc[rt][ct][reg] + bv;
      }
    if (cur >= 0) atomicAdd(&pool[cur * OUTD + col], run);
  }
  __syncthreads();
#pragma unroll
  for (int i = 0; i < 4; ++i) {
    int idx = tid * 4 + i;
    float v = pool[idx];
    if (v != 0.f) atomicAdd(&psum[idx], v);
  }
}

// ---------------------------------------------------------------------------
// Fused: GCN aggregation (+bias) -> LayerNorm -> ReLU -> residual (h bf16)
// Wave-per-node; lane owns 4 channels; m is fp8 e4m3 -> one dword gather/edge.
// ---------------------------------------------------------------------------
__global__ __launch_bounds__(256) void k_agg_ln(
    const unsigned char* __restrict__ m8, unsigned short* __restrict__ h,
    const int* __restrict__ row_ptr, const int* __restrict__ col_idx,
    const float* __restrict__ dinv, const float* __restrict__ bias,
    const float* __restrict__ gamma, const float* __restrict__ beta, int N) {
  int w = threadIdx.x >> 6, l = threadIdx.x & 63;
  int d = blockIdx.x * 4 + w;
  if (d >= N) return;
  int c0 = l * 4;
  float dv = dinv[d];

  // self loop
  unsigned int sv = *(const unsigned int*)&m8[((size_t)d << 8) + c0];
  f2v slo = __builtin_amdgcn_cvt_pk_f32_fp8(sv, 0);
  f2v shi = __builtin_amdgcn_cvt_pk_f32_fp8(sv, 1);
  float a0 = slo[0] * dv;
  float a1 = slo[1] * dv;
  float a2 = shi[0] * dv;
  float a3 = shi[1] * dv;

  int beg = row_ptr[d], end = row_ptr[d + 1];
#pragma unroll 4
  for (int jj = beg; jj < end; ++jj) {
    int s = col_idx[jj];
    float ws = dinv[s];
    unsigned int v = *(const unsigned int*)&m8[((size_t)s << 8) + c0];
    f2v lo = __builtin_amdgcn_cvt_pk_f32_fp8(v, 0);
    f2v hi = __builtin_amdgcn_cvt_pk_f32_fp8(v, 1);
    a0 += ws * lo[0];
    a1 += ws * lo[1];
    a2 += ws * hi[0];
    a3 += ws * hi[1];
  }

  float4 bv = *(const float4*)&bias[c0];
  a0 = a0 * dv + bv.x;
  a1 = a1 * dv + bv.y;
  a2 = a2 * dv + bv.z;
  a3 = a3 * dv + bv.w;

  float t = a0 + a1 + a2 + a3;
#pragma unroll
  for (int o = 32; o > 0; o >>= 1) t += __shfl_xor(t, o, 64);
  float mu = t * (1.f / 256.f);
  float d0 = a0 - mu, d1 = a1 - mu, d2 = a2 - mu, d3 = a3 - mu;
  float v2 = d0 * d0 + d1 * d1 + d2 * d2 + d3 * d3;
#pragma unroll
  for (int o = 32; o > 0; o >>= 1) v2 += __shfl_xor(v2, o, 64);
  float rs = rsqrtf(v2 * (1.f / 256.f) + LN_EPS);

  float4 gv = *(const float4*)&gamma[c0];
  float4 bt = *(const float4*)&beta[c0];
  uint2 hv = *(const uint2*)&h[(size_t)d * HID + c0];
  float y0 = fmaxf(d0 * rs * gv.x + bt.x, 0.f) + b2f_lo(hv.x);
  float y1 = fmaxf(d1 * rs * gv.y + bt.y, 0.f) + b2f_hi(hv.x);
  float y2 = fmaxf(d2 * rs * gv.z + bt.z, 0.f) + b2f_lo(hv.y);
  float y3 = fmaxf(d3 * rs * gv.w + bt.w, 0.f) + b2f_hi(hv.y);
  uint2 ov;
  ov.x = (unsigned int)f2b(y0) | ((unsigned int)f2b(y1) << 16);
  ov.y = (unsigned int)f2b(y2) | ((unsigned int)f2b(y3) << 16);
  *(uint2*)&h[(size_t)d * HID + c0] = ov;
}

// Final: out[b][c] = psum[b][c] / count(batch==b); counts via binary search.
__global__ void k_final(const float* __restrict__ psum, const int* __restrict__ batch,
                        float* __restrict__ out, int N) {
  int t = threadIdx.x;  // 1024 = 8*128
  int b = t >> 7;
  int lo = 0, hi = N;
  while (lo < hi) { int mid = (lo + hi) >> 1; if (batch[mid] < b) lo = mid + 1; else hi = mid; }
  int lb = lo;
  lo = 0; hi = N;
  while (lo < hi) { int mid = (lo + hi) >> 1; if (batch[mid] <= b) lo = mid + 1; else hi = mid; }
  int cnt = lo - lb;
  out[t] = psum[t] / fmaxf((float)cnt, 1.f);
}

// ---------------------------------------------------------------------------
extern "C" void kernel_launch(void* const* d_in, const int* in_sizes, int n_in,
                              void* d_out, int out_size, void* d_ws, size_t ws_size,
                              hipStream_t stream) {
  const float* x      = (const float*)d_in[0];
  const int*   ei     = (const int*)d_in[1];
  const int*   nt     = (const int*)d_in[2];
  const int*   batch  = (const int*)d_in[3];
  const float* emb    = (const float*)d_in[4];
  const float* W_in   = (const float*)d_in[5];
  const float* b_in   = (const float*)d_in[6];
  const float* Ws     = (const float*)d_in[7];
  const float* bs     = (const float*)d_in[8];
  const float* gammas = (const float*)d_in[9];
  const float* betas  = (const float*)d_in[10];
  const float* W_out  = (const float*)d_in[11];
  const float* b_out  = (const float*)d_in[12];
  float* out = (float*)d_out;

  const int N = in_sizes[2];
  const int E = in_sizes[1] / 2;
  const int nbuck = (N + 255) >> 8;
  const int epb = (E + NBLK - 1) / NBLK;

  auto align = [](size_t v) { return (v + 255) & ~(size_t)255; };
  char* p = (char*)d_ws;
  unsigned short* h = (unsigned short*)p; p += align((size_t)N * HID * 2);
  unsigned char* m8 = (unsigned char*)p;  p += align((size_t)N * HID);
  unsigned short* pk_in  = (unsigned short*)p; p += align(16 * 5 * 512 * 2);
  unsigned short* pk_sq  = (unsigned short*)p; p += align((size_t)3 * 16 * 8 * 512 * 2);
  unsigned short* pk_out = (unsigned short*)p; p += align(8 * 8 * 512 * 2);
  float* dinv = (float*)p;        p += align((size_t)N * 4);
  int* row_ptr = (int*)p;         p += align((size_t)(N + 1) * 4);
  int* col_idx = (int*)p;         p += align((size_t)E * 4);
  unsigned int* pairs = (unsigned int*)p; p += align((size_t)E * 4);
  int* blk_cnt = (int*)p;         p += align((size_t)NBLK * 256 * 4);
  int* blk_off = (int*)p;         p += align((size_t)NBLK * 256 * 4);
  int* bucket_cnt = (int*)p;      p += align(256 * 4);
  int* bucket_base = (int*)p;     p += align(257 * 4);
  float* psum = (float*)p;        p += align((size_t)NGRAPH * OUTD * 4);

  hipMemsetAsync(psum, 0, (size_t)NGRAPH * OUTD * 4, stream);

  // weight packing (tiny, one-time per launch)
  {
    int t_in = 16 * 5 * 512;
    k_pack<<<(t_in + 255) / 256, 256, 0, stream>>>(W_in, pk_in, HID, 5, t_in);
    int t_sq = 16 * 8 * 512;
    for (int lyr = 0; lyr < NLAYER; ++lyr)
      k_pack<<<(t_sq + 255) / 256, 256, 0, stream>>>(Ws + (size_t)lyr * HID * HID,
                                                     pk_sq + (size_t)lyr * t_sq, HID, 8, t_sq);
    int t_out = 8 * 8 * 512;
    k_pack<<<(t_out + 255) / 256, 256, 0, stream>>>(W_out, pk_out, OUTD, 8, t_out);
  }

  // CSR build (two-level counting sort, no global data atomics)
  k_b1<<<NBLK, 256, 0, stream>>>(ei + E, blk_cnt, E, epb);
  k_bsum<<<nbuck, 256, 0, stream>>>(blk_cnt, bucket_cnt);
  k_bscan<<<1, 256, 0, stream>>>(bucket_cnt, bucket_base, row_ptr, N, nbuck, E);
  k_boff<<<nbuck, 256, 0, stream>>>(blk_cnt, bucket_base, blk_off);
  k_b3<<<NBLK, 256, 0, stream>>>(ei, blk_off, pairs, E, epb);
  k_b4<<<nbuck, 256, 0, stream>>>(pairs, bucket_base, row_ptr, dinv, col_idx, N);

  const int GB = (N + 63) / 64;
  k_mfma_in<<<GB, 256, 0, stream>>>(x, nt, emb, pk_in, b_in, h, N);

  for (int lyr = 0; lyr < NLAYER; ++lyr) {
    k_mfma_sq<<<GB, 256, 0, stream>>>(h, pk_sq + (size_t)lyr * 16 * 8 * 512, m8, N);
    k_agg_ln<<<(N + 3) / 4, 256, 0, stream>>>(m8, h, row_ptr, col_idx, dinv,
                                              bs + (size_t)lyr * HID, gammas + (size_t)lyr * HID,
                                              betas + (size_t)lyr * HID, N);
  }

  k_mfma_out_pool<<<GB, 256, 0, stream>>>(h, pk_out, b_out, batch, psum, N);
  k_final<<<1, 1024, 0, stream>>>(psum, batch, out, N);
}

// Round 8
// 369.229 us; speedup vs baseline: 5.7972x; 1.0623x over previous
//
#include <hip/hip_runtime.h>
#include <math.h>

// Problem constants (match reference)
#define HID 256
#define DXIN 128
#define EMBD 32
#define OUTD 128
#define NLAYER 3
#define NGRAPH 8
#define LN_EPS 1e-5f
#define BKP 264   // LDS row stride (bf16 elems): 33 quads, 33%8==1 -> uniform banks
#define NBLK 256  // blocks for edge-binning passes

typedef short s8v __attribute__((ext_vector_type(8)));
typedef float f4v __attribute__((ext_vector_type(4)));
typedef float f2v __attribute__((ext_vector_type(2)));

__device__ __forceinline__ float b2f_lo(unsigned int u) {
  return __builtin_bit_cast(float, u << 16);
}
__device__ __forceinline__ float b2f_hi(unsigned int u) {
  return __builtin_bit_cast(float, u & 0xffff0000u);
}
__device__ __forceinline__ unsigned short f2b(float f) {
  unsigned int x = __builtin_bit_cast(unsigned int, f);
  unsigned int lsb = (x >> 16) & 1u;
  x += 0x7fffu + lsb;
  return (unsigned short)(x >> 16);
}

// ---------------------------------------------------------------------------
// CSR build via two-level counting sort (no global data atomics).
// bucket = dst >> 8 (<=256 buckets), dloc = dst & 255.
// ---------------------------------------------------------------------------
__global__ __launch_bounds__(256) void k_b1(const int* __restrict__ dst,
                                            int* __restrict__ blk_cnt, int E, int epb) {
  __shared__ int hist[256];
  int blk = blockIdx.x, tid = threadIdx.x;
  hist[tid] = 0;
  __syncthreads();
  int beg = blk * epb, end = min(E, beg + epb);
  for (int i = beg + tid; i < end; i += 256)
    atomicAdd(&hist[dst[i] >> 8], 1);
  __syncthreads();
  blk_cnt[blk * 256 + tid] = hist[tid];
}

__global__ __launch_bounds__(256) void k_bsum(const int* __restrict__ blk_cnt,
                                              int* __restrict__ bucket_cnt) {
  __shared__ int red[4];
  int b = blockIdx.x, tid = threadIdx.x;
  int v = blk_cnt[tid * 256 + b];
#pragma unroll
  for (int o = 32; o > 0; o >>= 1) v += __shfl_xor(v, o, 64);
  if ((tid & 63) == 0) red[tid >> 6] = v;
  __syncthreads();
  if (tid == 0) bucket_cnt[b] = red[0] + red[1] + red[2] + red[3];
}

__global__ __launch_bounds__(256) void k_bscan(const int* __restrict__ bucket_cnt,
                                               int* __restrict__ bucket_base,
                                               int* __restrict__ row_ptr,
                                               int N, int nbuck, int E) {
  __shared__ int s[256];
  int tid = threadIdx.x;
  int v = (tid < nbuck) ? bucket_cnt[tid] : 0;
  s[tid] = v;
  __syncthreads();
  for (int off = 1; off < 256; off <<= 1) {
    int t = (tid >= off) ? s[tid - off] : 0;
    __syncthreads();
    s[tid] += t;
    __syncthreads();
  }
  if (tid < nbuck) bucket_base[tid] = s[tid] - v;
  if (tid == 0) { bucket_base[nbuck] = E; row_ptr[N] = E; }
}

__global__ __launch_bounds__(256) void k_boff(const int* __restrict__ blk_cnt,
                                              const int* __restrict__ bucket_base,
                                              int* __restrict__ blk_off) {
  __shared__ int s[256];
  int b = blockIdx.x, tid = threadIdx.x;
  int v = blk_cnt[tid * 256 + b];
  s[tid] = v;
  __syncthreads();
  for (int off = 1; off < 256; off <<= 1) {
    int t = (tid >= off) ? s[tid - off] : 0;
    __syncthreads();
    s[tid] += t;
    __syncthreads();
  }
  blk_off[tid * 256 + b] = bucket_base[b] + s[tid] - v;
}

__global__ __launch_bounds__(256) void k_b3(const int* __restrict__ ei,
                                            const int* __restrict__ blk_off,
                                            unsigned int* __restrict__ pairs,
                                            int E, int epb) {
  __shared__ int cur[256];
  int blk = blockIdx.x, tid = threadIdx.x;
  cur[tid] = blk_off[blk * 256 + tid];
  __syncthreads();
  int beg = blk * epb, end = min(E, beg + epb);
  for (int i = beg + tid; i < end; i += 256) {
    int s = ei[i];
    int d = ei[E + i];
    int pos = atomicAdd(&cur[d >> 8], 1);
    pairs[pos] = (unsigned int)s | ((unsigned int)(d & 255) << 16);
  }
}

__global__ __launch_bounds__(256) void k_b4(const unsigned int* __restrict__ pairs,
                                            const int* __restrict__ bucket_base,
                                            int* __restrict__ row_ptr,
                                            float* __restrict__ dinv,
                                            int* __restrict__ col_idx, int N) {
  __shared__ int cnt[256];
  __shared__ int s[256];
  int b = blockIdx.x, tid = threadIdx.x;
  int base = bucket_base[b], end = bucket_base[b + 1];
  cnt[tid] = 0;
  __syncthreads();
  for (int i = base + tid; i < end; i += 256)
    atomicAdd(&cnt[pairs[i] >> 16], 1);
  __syncthreads();
  int c = cnt[tid];
  s[tid] = c;
  __syncthreads();
  for (int off = 1; off < 256; off <<= 1) {
    int t = (tid >= off) ? s[tid - off] : 0;
    __syncthreads();
    s[tid] += t;
    __syncthreads();
  }
  int excl = s[tid] - c;
  int d = (b << 8) + tid;
  if (d < N) {
    row_ptr[d] = base + excl;
    dinv[d] = rsqrtf((float)(c + 1));
  }
  __syncthreads();
  cnt[tid] = base + excl;  // reuse as cursor
  __syncthreads();
  for (int i = base + tid; i < end; i += 256) {
    unsigned int w = pairs[i];
    int pos = atomicAdd(&cnt[w >> 16], 1);
    col_idx[pos] = (int)(w & 0xFFFFu);
  }
}

// ---------------------------------------------------------------------------
// Weight pack (ALL weights in one launch): W [K][C] fp32 -> bf16 B-fragments.
// Segments: [0] W_in (NKS=5,C=256) | [1..3] Ws (NKS=8,C=256) | [4] W_out (NKS=8,C=128)
// ---------------------------------------------------------------------------
#define T_IN  (16 * 5 * 512)
#define T_SQ  (16 * 8 * 512)
#define T_OUT (8 * 8 * 512)
__global__ void k_pack_all(const float* __restrict__ W_in, const float* __restrict__ Ws,
                           const float* __restrict__ W_out,
                           unsigned short* __restrict__ pk_in,
                           unsigned short* __restrict__ pk_sq,
                           unsigned short* __restrict__ pk_out) {
  int t = blockIdx.x * 256 + threadIdx.x;
  const float* W;
  unsigned short* dst;
  int C, NKS;
  if (t < T_IN) {
    W = W_in; dst = pk_in; C = HID; NKS = 5;
  } else if (t < T_IN + 3 * T_SQ) {
    int tt = t - T_IN;
    int lyr = tt / T_SQ;
    t = tt - lyr * T_SQ;
    W = Ws + (size_t)lyr * HID * HID; dst = pk_sq + (size_t)lyr * T_SQ; C = HID; NKS = 8;
  } else if (t < T_IN + 3 * T_SQ + T_OUT) {
    t = t - T_IN - 3 * T_SQ;
    W = W_out; dst = pk_out; C = OUTD; NKS = 8;
  } else {
    return;
  }
  int j = t & 7;
  int l = (t >> 3) & 63;
  int rest = t >> 9;
  int ks = rest % NKS;
  int ct = rest / NKS;
  int k = ks * 32 + ((l >> 4) << 3) + j;
  int c = ct * 16 + (l & 15);
  dst[t] = f2b(W[(size_t)k * C + c]);
}

// ---------------------------------------------------------------------------
// MFMA GEMM: input projection  h = relu(concat(x, emb[nt]) @ W_in + b_in)
// ---------------------------------------------------------------------------
__global__ __launch_bounds__(256) void k_mfma_in(
    const float* __restrict__ x, const int* __restrict__ nt, const float* __restrict__ emb,
    const unsigned short* __restrict__ Wpk, const float* __restrict__ bias,
    unsigned short* __restrict__ h, int N) {
  __shared__ unsigned short a_lds[64 * BKP];
  int tid = threadIdx.x;
  int w = tid >> 6, l = tid & 63;
  int row0 = blockIdx.x * 64;

  for (int i = 0; i < 4; ++i) {
    int cc = i * 256 + tid;
    int r = cc >> 4, ch = cc & 15;
    int row = row0 + r;
    unsigned short tmp[8];
    if (row < N) {
      const float* xr = &x[(size_t)row * DXIN + ch * 8];
      float4 v0 = *(const float4*)xr;
      float4 v1 = *(const float4*)(xr + 4);
      tmp[0] = f2b(v0.x); tmp[1] = f2b(v0.y); tmp[2] = f2b(v0.z); tmp[3] = f2b(v0.w);
      tmp[4] = f2b(v1.x); tmp[5] = f2b(v1.y); tmp[6] = f2b(v1.z); tmp[7] = f2b(v1.w);
    } else {
      for (int q = 0; q < 8; ++q) tmp[q] = 0;
    }
    *(uint4*)&a_lds[r * BKP + ch * 8] = *(const uint4*)tmp;
  }
  {
    int r = tid >> 2, ch = tid & 3;
    int row = row0 + r;
    unsigned short tmp[8];
    if (row < N) {
      int typ = nt[row];
      const float* er = &emb[typ * EMBD + ch * 8];
      float4 v0 = *(const float4*)er;
      float4 v1 = *(const float4*)(er + 4);
      tmp[0] = f2b(v0.x); tmp[1] = f2b(v0.y); tmp[2] = f2b(v0.z); tmp[3] = f2b(v0.w);
      tmp[4] = f2b(v1.x); tmp[5] = f2b(v1.y); tmp[6] = f2b(v1.z); tmp[7] = f2b(v1.w);
    } else {
      for (int q = 0; q < 8; ++q) tmp[q] = 0;
    }
    *(uint4*)&a_lds[r * BKP + DXIN + ch * 8] = *(const uint4*)tmp;
  }
  __syncthreads();

  f4v acc[4][4];
#pragma unroll
  for (int rt = 0; rt < 4; ++rt)
#pragma unroll
    for (int ct = 0; ct < 4; ++ct) acc[rt][ct] = (f4v)0.f;

  for (int ks = 0; ks < 5; ++ks) {
    s8v af[4];
#pragma unroll
    for (int rt = 0; rt < 4; ++rt)
      af[rt] = *(const s8v*)&a_lds[(rt * 16 + (l & 15)) * BKP + ks * 32 + (l >> 4) * 8];
#pragma unroll
    for (int ct = 0; ct < 4; ++ct) {
      s8v bf = *(const s8v*)&Wpk[(size_t)(((w * 4 + ct) * 5 + ks) * 64 + l) * 8];
#pragma unroll
      for (int rt = 0; rt < 4; ++rt)
        acc[rt][ct] = __builtin_amdgcn_mfma_f32_16x16x32_bf16(af[rt], bf, acc[rt][ct], 0, 0, 0);
    }
  }
  __syncthreads();

#pragma unroll
  for (int rt = 0; rt < 4; ++rt)
#pragma unroll
    for (int ct = 0; ct < 4; ++ct) {
      int col = w * 64 + ct * 16 + (l & 15);
      float bv = bias[col];
#pragma unroll
      for (int reg = 0; reg < 4; ++reg) {
        int r = rt * 16 + (l >> 4) * 4 + reg;
        a_lds[r * BKP + col] = f2b(fmaxf(acc[rt][ct][reg] + bv, 0.f));
      }
    }
  __syncthreads();
  for (int i = 0; i < 8; ++i) {
    int cc = i * 256 + tid;
    int r = cc >> 5, ch = cc & 31;
    int row = row0 + r;
    if (row < N)
      *(uint4*)&h[(size_t)row * HID + ch * 8] = *(const uint4*)&a_lds[r * BKP + ch * 8];
  }
}

// ---------------------------------------------------------------------------
// MFMA GEMM: square layer  m8 = fp8((h @ W) * dinv[row])  (pre-scaled by src norm)
// ---------------------------------------------------------------------------
__global__ __launch_bounds__(256) void k_mfma_sq(
    const unsigned short* __restrict__ A, const unsigned short* __restrict__ Wpk,
    const float* __restrict__ dinv, unsigned char* __restrict__ m8, int N) {
  __shared__ unsigned short a_lds[64 * BKP];
  int tid = threadIdx.x;
  int w = tid >> 6, l = tid & 63;
  int row0 = blockIdx.x * 64;

  for (int i = 0; i < 8; ++i) {
    int cc = i * 256 + tid;
    int r = cc >> 5, ch = cc & 31;
    int row = row0 + r;
    uint4 v = make_uint4(0u, 0u, 0u, 0u);
    if (row < N) v = *(const uint4*)&A[(size_t)row * HID + ch * 8];
    *(uint4*)&a_lds[r * BKP + ch * 8] = v;
  }
  __syncthreads();

  f4v acc[4][4];
#pragma unroll
  for (int rt = 0; rt < 4; ++rt)
#pragma unroll
    for (int ct = 0; ct < 4; ++ct) acc[rt][ct] = (f4v)0.f;

  for (int ks = 0; ks < 8; ++ks) {
    s8v af[4];
#pragma unroll
    for (int rt = 0; rt < 4; ++rt)
      af[rt] = *(const s8v*)&a_lds[(rt * 16 + (l & 15)) * BKP + ks * 32 + (l >> 4) * 8];
#pragma unroll
    for (int ct = 0; ct < 4; ++ct) {
      s8v bf = *(const s8v*)&Wpk[(size_t)(((w * 4 + ct) * 8 + ks) * 64 + l) * 8];
#pragma unroll
      for (int rt = 0; rt < 4; ++rt)
        acc[rt][ct] = __builtin_amdgcn_mfma_f32_16x16x32_bf16(af[rt], bf, acc[rt][ct], 0, 0, 0);
    }
  }
  __syncthreads();

  // transpose via LDS (bf16), then scale by dinv[row] + convert to fp8 on store
#pragma unroll
  for (int rt = 0; rt < 4; ++rt)
#pragma unroll
    for (int ct = 0; ct < 4; ++ct) {
      int col = w * 64 + ct * 16 + (l & 15);
#pragma unroll
      for (int reg = 0; reg < 4; ++reg) {
        int r = rt * 16 + (l >> 4) * 4 + reg;
        a_lds[r * BKP + col] = f2b(acc[rt][ct][reg]);
      }
    }
  __syncthreads();
  for (int i = 0; i < 8; ++i) {
    int cc = i * 256 + tid;
    int r = cc >> 5, ch = cc & 31;
    int row = row0 + r;
    if (row < N) {
      float dv = dinv[row];
      uint4 v = *(const uint4*)&a_lds[r * BKP + ch * 8];
      float f0 = b2f_lo(v.x) * dv, f1 = b2f_hi(v.x) * dv;
      float f2 = b2f_lo(v.y) * dv, f3 = b2f_hi(v.y) * dv;
      float f4 = b2f_lo(v.z) * dv, f5 = b2f_hi(v.z) * dv;
      float f6 = b2f_lo(v.w) * dv, f7 = b2f_hi(v.w) * dv;
      unsigned int p0 = 0, p1 = 0;
      p0 = __builtin_amdgcn_cvt_pk_fp8_f32(f0, f1, p0, 0);
      p0 = __builtin_amdgcn_cvt_pk_fp8_f32(f2, f3, p0, 1);
      p1 = __builtin_amdgcn_cvt_pk_fp8_f32(f4, f5, p1, 0);
      p1 = __builtin_amdgcn_cvt_pk_fp8_f32(f6, f7, p1, 1);
      *(uint2*)&m8[(size_t)row * HID + ch * 8] = make_uint2(p0, p1);
    }
  }
}

// ---------------------------------------------------------------------------
// MFMA GEMM: output layer (C=128) + bias + mean-pool partials via LDS bins.
// ---------------------------------------------------------------------------
__global__ __launch_bounds__(256) void k_mfma_out_pool(
    const unsigned short* __restrict__ A, const unsigned short* __restrict__ Wpk,
    const float* __restrict__ bias, const int* __restrict__ batch,
    float* __restrict__ psum, int N) {
  __shared__ unsigned short a_lds[64 * BKP];
  __shared__ float pool[NGRAPH * OUTD];
  __shared__ int b_s[64];
  int tid = threadIdx.x;
  int w = tid >> 6, l = tid & 63;
  int row0 = blockIdx.x * 64;

#pragma unroll
  for (int i = 0; i < 4; ++i) pool[tid * 4 + i] = 0.f;
  if (tid < 64) b_s[tid] = (row0 + tid < N) ? batch[row0 + tid] : -1;

  for (int i = 0; i < 8; ++i) {
    int cc = i * 256 + tid;
    int r = cc >> 5, ch = cc & 31;
    int row = row0 + r;
    uint4 v = make_uint4(0u, 0u, 0u, 0u);
    if (row < N) v = *(const uint4*)&A[(size_t)row * HID + ch * 8];
    *(uint4*)&a_lds[r * BKP + ch * 8] = v;
  }
  __syncthreads();

  f4v acc[4][2];
#pragma unroll
  for (int rt = 0; rt < 4; ++rt)
#pragma unroll
    for (int ct = 0; ct < 2; ++ct) acc[rt][ct] = (f4v)0.f;

  for (int ks = 0; ks < 8; ++ks) {
    s8v af[4];
#pragma unroll
    for (int rt = 0; rt < 4; ++rt)
      af[rt] = *(const s8v*)&a_lds[(rt * 16 + (l & 15)) * BKP + ks * 32 + (l >> 4) * 8];
#pragma unroll
    for (int ct = 0; ct < 2; ++ct) {
      s8v bf = *(const s8v*)&Wpk[(size_t)(((w * 2 + ct) * 8 + ks) * 64 + l) * 8];
#pragma unroll
      for (int rt = 0; rt < 4; ++rt)
        acc[rt][ct] = __builtin_amdgcn_mfma_f32_16x16x32_bf16(af[rt], bf, acc[rt][ct], 0, 0, 0);
    }
  }

#pragma unroll
  for (int ct = 0; ct < 2; ++ct) {
    int col = w * 32 + ct * 16 + (l & 15);
    float bv = bias[col];
    float run = 0.f;
    int cur = -1;
#pragma unroll
    for (int rt = 0; rt < 4; ++rt)
#pragma unroll
      for (int reg = 0; reg < 4; ++reg) {
        int rrel = rt * 16 + (l >> 4) * 4 + reg;
        int g = b_s[rrel];
        if (g != cur) {
          if (cur >= 0) atomicAdd(&pool[cur * OUTD + col], run);
          run = 0.f;
          cur = g;
        }
        if (g >= 0) run += acc[rt][ct][reg] + bv;
      }
    if (cur >= 0) atomicAdd(&pool[cur * OUTD + col], run);
  }
  __syncthreads();
#pragma unroll
  for (int i = 0; i < 4; ++i) {
    int idx = tid * 4 + i;
    float v = pool[idx];
    if (v != 0.f) atomicAdd(&psum[idx], v);
  }
}

// ---------------------------------------------------------------------------
// Fused: GCN aggregation (+bias) -> LayerNorm -> ReLU -> residual (h bf16)
// Wave-per-node; lane owns 4 channels; m8 rows pre-scaled by dinv[src] ->
// per-edge work is one dword gather + 2 cvt + 4 add. 8-deep load batching.
// ---------------------------------------------------------------------------
__global__ __launch_bounds__(256) void k_agg_ln(
    const unsigned char* __restrict__ m8, unsigned short* __restrict__ h,
    const int* __restrict__ row_ptr, const int* __restrict__ col_idx,
    const float* __restrict__ dinv, const float* __restrict__ bias,
    const float* __restrict__ gamma, const float* __restrict__ beta, int N) {
  int w = threadIdx.x >> 6, l = threadIdx.x & 63;
  int d = blockIdx.x * 4 + w;
  if (d >= N) return;
  int c0 = l * 4;
  float dv = dinv[d];

  // self loop (m8 already carries dinv[d])
  unsigned int sv = *(const unsigned int*)&m8[((size_t)d << 8) + c0];
  f2v slo = __builtin_amdgcn_cvt_pk_f32_fp8(sv, 0);
  f2v shi = __builtin_amdgcn_cvt_pk_f32_fp8(sv, 1);
  float a0 = slo[0];
  float a1 = slo[1];
  float a2 = shi[0];
  float a3 = shi[1];

  int beg = row_ptr[d], end = row_ptr[d + 1];
  int jj = beg;
  for (; jj + 8 <= end; jj += 8) {
    unsigned int vv[8];
#pragma unroll
    for (int q = 0; q < 8; ++q) {
      int s = col_idx[jj + q];
      vv[q] = *(const unsigned int*)&m8[((size_t)s << 8) + c0];
    }
#pragma unroll
    for (int q = 0; q < 8; ++q) {
      f2v lo = __builtin_amdgcn_cvt_pk_f32_fp8(vv[q], 0);
      f2v hi = __builtin_amdgcn_cvt_pk_f32_fp8(vv[q], 1);
      a0 += lo[0];
      a1 += lo[1];
      a2 += hi[0];
      a3 += hi[1];
    }
  }
  for (; jj < end; ++jj) {
    int s = col_idx[jj];
    unsigned int v = *(const unsigned int*)&m8[((size_t)s << 8) + c0];
    f2v lo = __builtin_amdgcn_cvt_pk_f32_fp8(v, 0);
    f2v hi = __builtin_amdgcn_cvt_pk_f32_fp8(v, 1);
    a0 += lo[0];
    a1 += lo[1];
    a2 += hi[0];
    a3 += hi[1];
  }

  float4 bv = *(const float4*)&bias[c0];
  a0 = a0 * dv + bv.x;
  a1 = a1 * dv + bv.y;
  a2 = a2 * dv + bv.z;
  a3 = a3 * dv + bv.w;

  float t = a0 + a1 + a2 + a3;
#pragma unroll
  for (int o = 32; o > 0; o >>= 1) t += __shfl_xor(t, o, 64);
  float mu = t * (1.f / 256.f);
  float d0 = a0 - mu, d1 = a1 - mu, d2 = a2 - mu, d3 = a3 - mu;
  float v2 = d0 * d0 + d1 * d1 + d2 * d2 + d3 * d3;
#pragma unroll
  for (int o = 32; o > 0; o >>= 1) v2 += __shfl_xor(v2, o, 64);
  float rs = rsqrtf(v2 * (1.f / 256.f) + LN_EPS);

  float4 gv = *(const float4*)&gamma[c0];
  float4 bt = *(const float4*)&beta[c0];
  uint2 hv = *(const uint2*)&h[(size_t)d * HID + c0];
  float y0 = fmaxf(d0 * rs * gv.x + bt.x, 0.f) + b2f_lo(hv.x);
  float y1 = fmaxf(d1 * rs * gv.y + bt.y, 0.f) + b2f_hi(hv.x);
  float y2 = fmaxf(d2 * rs * gv.z + bt.z, 0.f) + b2f_lo(hv.y);
  float y3 = fmaxf(d3 * rs * gv.w + bt.w, 0.f) + b2f_hi(hv.y);
  uint2 ov;
  ov.x = (unsigned int)f2b(y0) | ((unsigned int)f2b(y1) << 16);
  ov.y = (unsigned int)f2b(y2) | ((unsigned int)f2b(y3) << 16);
  *(uint2*)&h[(size_t)d * HID + c0] = ov;
}

// Final: out[b][c] = psum[b][c] / count(batch==b); counts via binary search.
__global__ void k_final(const float* __restrict__ psum, const int* __restrict__ batch,
                        float* __restrict__ out, int N) {
  int t = threadIdx.x;  // 1024 = 8*128
  int b = t >> 7;
  int lo = 0, hi = N;
  while (lo < hi) { int mid = (lo + hi) >> 1; if (batch[mid] < b) lo = mid + 1; else hi = mid; }
  int lb = lo;
  lo = 0; hi = N;
  while (lo < hi) { int mid = (lo + hi) >> 1; if (batch[mid] <= b) lo = mid + 1; else hi = mid; }
  int cnt = lo - lb;
  out[t] = psum[t] / fmaxf((float)cnt, 1.f);
}

// ---------------------------------------------------------------------------
extern "C" void kernel_launch(void* const* d_in, const int* in_sizes, int n_in,
                              void* d_out, int out_size, void* d_ws, size_t ws_size,
                              hipStream_t stream) {
  const float* x      = (const float*)d_in[0];
  const int*   ei     = (const int*)d_in[1];
  const int*   nt     = (const int*)d_in[2];
  const int*   batch  = (const int*)d_in[3];
  const float* emb    = (const float*)d_in[4];
  const float* W_in   = (const float*)d_in[5];
  const float* b_in   = (const float*)d_in[6];
  const float* Ws     = (const float*)d_in[7];
  const float* bs     = (const float*)d_in[8];
  const float* gammas = (const float*)d_in[9];
  const float* betas  = (const float*)d_in[10];
  const float* W_out  = (const float*)d_in[11];
  const float* b_out  = (const float*)d_in[12];
  float* out = (float*)d_out;

  const int N = in_sizes[2];
  const int E = in_sizes[1] / 2;
  const int nbuck = (N + 255) >> 8;
  const int epb = (E + NBLK - 1) / NBLK;

  auto align = [](size_t v) { return (v + 255) & ~(size_t)255; };
  char* p = (char*)d_ws;
  unsigned short* h = (unsigned short*)p; p += align((size_t)N * HID * 2);
  unsigned char* m8 = (unsigned char*)p;  p += align((size_t)N * HID);
  unsigned short* pk_in  = (unsigned short*)p; p += align((size_t)T_IN * 2);
  unsigned short* pk_sq  = (unsigned short*)p; p += align((size_t)3 * T_SQ * 2);
  unsigned short* pk_out = (unsigned short*)p; p += align((size_t)T_OUT * 2);
  float* dinv = (float*)p;        p += align((size_t)N * 4);
  int* row_ptr = (int*)p;         p += align((size_t)(N + 1) * 4);
  int* col_idx = (int*)p;         p += align((size_t)E * 4);
  unsigned int* pairs = (unsigned int*)p; p += align((size_t)E * 4);
  int* blk_cnt = (int*)p;         p += align((size_t)NBLK * 256 * 4);
  int* blk_off = (int*)p;         p += align((size_t)NBLK * 256 * 4);
  int* bucket_cnt = (int*)p;      p += align(256 * 4);
  int* bucket_base = (int*)p;     p += align(257 * 4);
  float* psum = (float*)p;        p += align((size_t)NGRAPH * OUTD * 4);

  hipMemsetAsync(psum, 0, (size_t)NGRAPH * OUTD * 4, stream);

  // weight packing: single launch for all weights
  {
    int total = T_IN + 3 * T_SQ + T_OUT;
    k_pack_all<<<(total + 255) / 256, 256, 0, stream>>>(W_in, Ws, W_out,
                                                        pk_in, pk_sq, pk_out);
  }

  // CSR build (two-level counting sort, no global data atomics)
  k_b1<<<NBLK, 256, 0, stream>>>(ei + E, blk_cnt, E, epb);
  k_bsum<<<nbuck, 256, 0, stream>>>(blk_cnt, bucket_cnt);
  k_bscan<<<1, 256, 0, stream>>>(bucket_cnt, bucket_base, row_ptr, N, nbuck, E);
  k_boff<<<nbuck, 256, 0, stream>>>(blk_cnt, bucket_base, blk_off);
  k_b3<<<NBLK, 256, 0, stream>>>(ei, blk_off, pairs, E, epb);
  k_b4<<<nbuck, 256, 0, stream>>>(pairs, bucket_base, row_ptr, dinv, col_idx, N);

  const int GB = (N + 63) / 64;
  k_mfma_in<<<GB, 256, 0, stream>>>(x, nt, emb, pk_in, b_in, h, N);

  for (int lyr = 0; lyr < NLAYER; ++lyr) {
    k_mfma_sq<<<GB, 256, 0, stream>>>(h, pk_sq + (size_t)lyr * T_SQ, dinv, m8, N);
    k_agg_ln<<<(N + 3) / 4, 256, 0, stream>>>(m8, h, row_ptr, col_idx, dinv,
                                              bs + (size_t)lyr * HID, gammas + (size_t)lyr * HID,
                                              betas + (size_t)lyr * HID, N);
  }

  k_mfma_out_pool<<<GB, 256, 0, stream>>>(h, pk_out, b_out, batch, psum, N);
  k_final<<<1, 1024, 0, stream>>>(psum, batch, out, N);
}